// Round 10
// baseline (892.718 us; speedup 1.0000x reference)
//
#include <hip/hip_runtime.h>

// GCNPre: N=100000 nodes, E=3200000 edges, F=512, H=256, C=40.
#define NN 100000
#define NE 3200000
#define NF 512
#define NH 256
#define NC 40

// CSR-build partitioning (round-8 structure: 256+ blocks, u8 partials).
#define CH 32768
#define NCH 4
#define NPAD (NCH * CH)              // 131072
#define PARTS 64
#define SLICE ((NE + PARTS - 1) / PARTS)   // 50000
#define NBLK ((NN + 255) / 256)      // 391

// Feature-group blocking for aggregation: 16 planes of [NN][16] bf16 (3.2MB, L2-fits).
#define GB 16
#define GF 16
#define NPB 128                      // nodes per agg block
#define ECAP 8192                    // LDS edge capacity (mean 4096, +64 sigma)

typedef __attribute__((ext_vector_type(8))) short bf16x8;
typedef __attribute__((ext_vector_type(4))) float f32x4;
typedef __attribute__((ext_vector_type(4))) unsigned short u16x4;
typedef __attribute__((ext_vector_type(8))) unsigned short u16x8;

__device__ inline unsigned short f2bf(float f) {
    union { float f; unsigned u; } v; v.f = f;
    unsigned r = v.u + 0x7fffu + ((v.u >> 16) & 1u);
    return (unsigned short)(r >> 16);
}
__device__ inline float bf2f(unsigned short s) {
    union { unsigned u; float f; } v; v.u = ((unsigned)s) << 16;
    return v.f;
}

// ---------------- CSR build (no global atomics) ----------------

__global__ __launch_bounds__(512) void hist2_kernel(const int* __restrict__ ei,
                                                    unsigned char* __restrict__ rpart8,
                                                    unsigned char* __restrict__ cpart8) {
    __shared__ unsigned h[CH / 2];   // u16-packed counters, 64KB
    const int chunk = blockIdx.x, part = blockIdx.y, which = blockIdx.z;
    const int* src = which ? (ei + NE) : ei;
    unsigned char* outp = which ? cpart8 : rpart8;
    const int lo = chunk * CH;
    for (int i = threadIdx.x; i < CH / 2; i += 512) h[i] = 0;
    __syncthreads();
    const int e1 = min((part + 1) * SLICE, NE);
    for (int e = part * SLICE + threadIdx.x; e < e1; e += 512) {
        unsigned v = (unsigned)(src[e] - lo);
        if (v < CH) atomicAdd(&h[v >> 1], 1u << ((v & 1) << 4));
    }
    __syncthreads();
    unsigned char* dst = outp + (size_t)part * NPAD + lo;
    for (int i = threadIdx.x; i < CH; i += 512)
        dst[i] = (unsigned char)((h[i >> 1] >> ((i & 1) << 4)) & 0xffu);
}

__global__ __launch_bounds__(256) void reduce_kernel(const unsigned char* __restrict__ rpart8,
                                                     const unsigned char* __restrict__ cpart8,
                                                     int* __restrict__ row_cnt, float* __restrict__ dis,
                                                     int* __restrict__ bsum) {
    __shared__ int s[256];
    const int tid = threadIdx.x;
    const int v = blockIdx.x * 256 + tid;
    unsigned rs = 0, cs = 0;
    if (v < NN) {
        #pragma unroll 1
        for (int p = 0; p < PARTS; p++) {
            rs += rpart8[(size_t)p * NPAD + v];
            cs += cpart8[(size_t)p * NPAD + v];
        }
        row_cnt[v] = (int)rs;
        dis[v] = rsqrtf((float)cs + 1.0f);
    }
    s[tid] = (int)rs;
    __syncthreads();
    #pragma unroll
    for (int o = 128; o > 0; o >>= 1) {
        if (tid < o) s[tid] += s[tid + o];
        __syncthreads();
    }
    if (tid == 0) bsum[blockIdx.x] = s[0];
}

__global__ __launch_bounds__(512) void scanb_kernel(const int* __restrict__ bsum,
                                                    int* __restrict__ boff) {
    __shared__ int s[512];
    const int t = threadIdx.x;
    int v = (t < NBLK) ? bsum[t] : 0;
    s[t] = v;
    __syncthreads();
    #pragma unroll
    for (int o = 1; o < 512; o <<= 1) {
        int u = (t >= o) ? s[t - o] : 0;
        __syncthreads();
        s[t] += u;
        __syncthreads();
    }
    if (t < NBLK) boff[t] = s[t] - v;   // exclusive
}

__global__ __launch_bounds__(256) void rstart2_kernel(const unsigned char* __restrict__ rpart8,
                                                      const int* __restrict__ row_cnt,
                                                      const int* __restrict__ boff,
                                                      int* __restrict__ row_ptr,
                                                      unsigned* __restrict__ rbase) {
    __shared__ int s[256];
    const int tid = threadIdx.x;
    const int v = blockIdx.x * 256 + tid;
    int cnt = (v < NN) ? row_cnt[v] : 0;
    s[tid] = cnt;
    __syncthreads();
    #pragma unroll
    for (int o = 1; o < 256; o <<= 1) {
        int u = (tid >= o) ? s[tid - o] : 0;
        __syncthreads();
        s[tid] += u;
        __syncthreads();
    }
    if (v < NN) {
        unsigned run = (unsigned)(boff[blockIdx.x] + s[tid] - cnt);
        row_ptr[v] = (int)run;
        #pragma unroll 1
        for (int p = 0; p < PARTS; p++) {
            size_t i = (size_t)p * NPAD + v;
            rbase[i] = run;
            run += rpart8[i];
        }
    }
    if (v == NN) row_ptr[NN] = NE;
}

// Fill csr (col only, 4B records) with packed-u16 LDS cursors. Plain 2D grid (r8 style).
__global__ __launch_bounds__(512) void fill2d_kernel(const int* __restrict__ ei,
                                                     const unsigned* __restrict__ rbase,
                                                     int* __restrict__ csr) {
    __shared__ unsigned cur[CH / 2];
    const int chunk = blockIdx.x, part = blockIdx.y;
    const int lo = chunk * CH;
    for (int i = threadIdx.x; i < CH / 2; i += 512) cur[i] = 0;
    __syncthreads();
    const unsigned* base = rbase + (size_t)part * NPAD + lo;
    const int e1 = min((part + 1) * SLICE, NE);
    for (int e = part * SLICE + threadIdx.x; e < e1; e += 512) {
        int r = ei[e];
        unsigned rr = (unsigned)(r - lo);
        if (rr < CH) {
            int c = ei[NE + e];
            unsigned sh = (rr & 1) << 4;
            unsigned old = atomicAdd(&cur[rr >> 1], 1u << sh);
            unsigned p = (old >> sh) & 0xffffu;
            csr[base[rr] + p] = c;
        }
    }
}

// ---------------- weight transpose + bf16 cast, PRE-SWIZZLED for global_load_lds ----
__global__ void wtrans_all(const float* __restrict__ Wm, const float* __restrict__ W1,
                           const float* __restrict__ W2, unsigned short* __restrict__ WTm,
                           unsigned short* __restrict__ W1T, unsigned short* __restrict__ W2T) {
    int t = blockIdx.x * 256 + threadIdx.x;
    if (t < NH * NF) {
        int n = t / NF, k = t % NF;
        int sw = ((k >> 3) & 3) ^ (n & 3) ^ ((n >> 2) & 3);
        WTm[n * NF + (k & ~31) + (sw << 3) + (k & 7)] = f2bf(Wm[(long)k * NH + n]);
        return;
    }
    t -= NH * NF;
    if (t < NH * NH) {
        int n = t / NH, k = t % NH;
        int sw = ((k >> 3) & 3) ^ (n & 3) ^ ((n >> 2) & 3);
        W1T[n * NH + (k & ~31) + (sw << 3) + (k & 7)] = f2bf(W1[(long)k * NH + n]);
        return;
    }
    t -= NH * NH;
    if (t < 64 * NH) {
        int n = t / NH, k = t % NH;
        int sw = ((k >> 3) & 3) ^ (n & 3) ^ ((n >> 2) & 3);
        W2T[n * NH + (k & ~31) + (sw << 3) + (k & 7)] =
            (n < NC) ? f2bf(W2[(long)k * NC + n]) : (unsigned short)0;
    }
}

// ---------------- fused GEMM1+GEMM2 (t1 written group-blocked [16][NN][16]) ----------------
__global__ __launch_bounds__(512)
void gemm12_kernel(const float* __restrict__ x, const unsigned short* __restrict__ WTm,
                   const float* __restrict__ bmlp, const unsigned short* __restrict__ W1T,
                   unsigned short* __restrict__ t1, int M) {
    __shared__ short h0s[128 * 256];   // 64KB; [0..8KB)=stage1 As, [8KB..24KB)=stage1 Bs
    __shared__ short Bs2[256 * 32];    // 16KB stage-2 B

    const int tid = threadIdx.x;
    const int lane = tid & 63;
    const int wid = tid >> 6;
    const int wr = wid >> 1;
    const int wc = wid & 1;
    const long bm = (long)blockIdx.x * 128;
    const int l15 = lane & 15, g = lane >> 4, l4 = lane >> 4;

    f32x4 acc[2][8];
    #pragma unroll
    for (int i = 0; i < 2; i++)
        #pragma unroll
        for (int j = 0; j < 8; j++) acc[i][j] = (f32x4){0.f, 0.f, 0.f, 0.f};

    // ---- stage 1: K = 512 over x (fp32) and WTm (global_load_lds, pre-swizzled) ----
    for (int k0 = 0; k0 < NF; k0 += 32) {
        #pragma unroll
        for (int i = 0; i < 2; i++) {
            int ch = tid + i * 512;
            __builtin_amdgcn_global_load_lds(
                (const void*)(WTm + (size_t)(ch >> 2) * NF + k0 + (ch & 3) * 8),
                (void*)(&h0s[4096 + ch * 8]), 16, 0, 0);
        }
        {
            int ch = tid;
            int row = ch >> 2, c = ch & 3;
            int sw = c ^ (row & 3) ^ ((row >> 2) & 3);
            long gr = bm + row;
            bf16x8 w = (bf16x8){0, 0, 0, 0, 0, 0, 0, 0};
            if (gr < M) {
                float4 v0 = *(const float4*)(x + gr * NF + k0 + c * 8);
                float4 v1 = *(const float4*)(x + gr * NF + k0 + c * 8 + 4);
                w[0] = (short)f2bf(v0.x); w[1] = (short)f2bf(v0.y);
                w[2] = (short)f2bf(v0.z); w[3] = (short)f2bf(v0.w);
                w[4] = (short)f2bf(v1.x); w[5] = (short)f2bf(v1.y);
                w[6] = (short)f2bf(v1.z); w[7] = (short)f2bf(v1.w);
            }
            *(bf16x8*)(&h0s[row * 32 + sw * 8]) = w;
        }
        __syncthreads();

        bf16x8 a[2];
        #pragma unroll
        for (int mi = 0; mi < 2; mi++) {
            int row = wr * 32 + mi * 16 + l15;
            int sw = g ^ (row & 3) ^ ((row >> 2) & 3);
            a[mi] = *(const bf16x8*)(&h0s[row * 32 + sw * 8]);
        }
        #pragma unroll
        for (int ni = 0; ni < 8; ni++) {
            int row = wc * 128 + ni * 16 + l15;
            int sw = g ^ (row & 3) ^ ((row >> 2) & 3);
            bf16x8 b = *(const bf16x8*)(&h0s[4096 + row * 32 + sw * 8]);
            #pragma unroll
            for (int mi = 0; mi < 2; mi++)
                acc[mi][ni] = __builtin_amdgcn_mfma_f32_16x16x32_bf16(a[mi], b, acc[mi][ni], 0, 0, 0);
        }
        __syncthreads();
    }

    // ---- h0 tile (relu+bias, bf16) -> LDS, chunk-swizzled
    #pragma unroll
    for (int mi = 0; mi < 2; mi++) {
        int r0 = wr * 32 + mi * 16 + l4 * 4;
        #pragma unroll
        for (int ni = 0; ni < 8; ni++) {
            int gc = wc * 128 + ni * 16 + l15;
            float bv = bmlp[gc];
            int cc = gc >> 3, c7 = gc & 7;
            #pragma unroll
            for (int q = 0; q < 4; q++) {
                int row = r0 + q;
                float v = fmaxf(acc[mi][ni][q] + bv, 0.f);
                h0s[row * 256 + ((cc ^ (row & 7)) << 3) + c7] = (short)f2bf(v);
            }
        }
    }

    #pragma unroll
    for (int i = 0; i < 2; i++)
        #pragma unroll
        for (int j = 0; j < 8; j++) acc[i][j] = (f32x4){0.f, 0.f, 0.f, 0.f};

    // ---- stage 2: K = 256 over h0s and W1T ----
    for (int k2 = 0; k2 < NH; k2 += 32) {
        #pragma unroll
        for (int i = 0; i < 2; i++) {
            int ch = tid + i * 512;
            __builtin_amdgcn_global_load_lds(
                (const void*)(W1T + (size_t)(ch >> 2) * NH + k2 + (ch & 3) * 8),
                (void*)(&Bs2[ch * 8]), 16, 0, 0);
        }
        __syncthreads();

        bf16x8 a[2];
        #pragma unroll
        for (int mi = 0; mi < 2; mi++) {
            int row = wr * 32 + mi * 16 + l15;
            int cc = (k2 >> 3) + g;
            a[mi] = *(const bf16x8*)(&h0s[row * 256 + ((cc ^ (row & 7)) << 3)]);
        }
        #pragma unroll
        for (int ni = 0; ni < 8; ni++) {
            int row = wc * 128 + ni * 16 + l15;
            int sw = g ^ (row & 3) ^ ((row >> 2) & 3);
            bf16x8 b = *(const bf16x8*)(&Bs2[row * 32 + sw * 8]);
            #pragma unroll
            for (int mi = 0; mi < 2; mi++)
                acc[mi][ni] = __builtin_amdgcn_mfma_f32_16x16x32_bf16(a[mi], b, acc[mi][ni], 0, 0, 0);
        }
        __syncthreads();
    }

    // ---- t1 write, group-blocked: t1[(gc>>4)*NN*16 + gr*16 + (gc&15)]
    #pragma unroll
    for (int mi = 0; mi < 2; mi++) {
        long gr0 = bm + wr * 32 + mi * 16 + l4 * 4;
        #pragma unroll
        for (int ni = 0; ni < 8; ni++) {
            int gc = wc * 128 + ni * 16 + l15;
            unsigned short* pl = t1 + (size_t)(gc >> 4) * NN * GF + (gc & 15);
            #pragma unroll
            for (int q = 0; q < 4; q++) {
                long gr = gr0 + q;
                if (gr < M) pl[gr * GF] = f2bf(acc[mi][ni][q]);
            }
        }
    }
}

// ---------------- GEMM3 (blocked h1 @ W2 -> t2p ldc=40) ----------------
__global__ __launch_bounds__(256)
void gemm3_kernel(const unsigned short* __restrict__ A, const unsigned short* __restrict__ W2T,
                  unsigned short* __restrict__ C, int M) {
    constexpr int BM = 128, BK = 32;
    __shared__ short As[BM * BK];
    __shared__ short Bs[64 * BK];

    const int tid = threadIdx.x;
    const int lane = tid & 63;
    const int wid = tid >> 6;
    const int wr = wid;
    const long bm = (long)blockIdx.x * BM;
    const int l15 = lane & 15, g = lane >> 4, l4 = lane >> 4;

    f32x4 acc[2][4];
    #pragma unroll
    for (int i = 0; i < 2; i++)
        #pragma unroll
        for (int j = 0; j < 4; j++) acc[i][j] = (f32x4){0.f, 0.f, 0.f, 0.f};

    for (int k0 = 0; k0 < NH; k0 += BK) {
        {
            int ch = tid;
            __builtin_amdgcn_global_load_lds(
                (const void*)(W2T + (size_t)(ch >> 2) * NH + k0 + (ch & 3) * 8),
                (void*)(&Bs[ch * 8]), 16, 0, 0);
        }
        #pragma unroll
        for (int i = 0; i < 2; i++) {
            int ch = tid + i * 256;
            int row = ch >> 2, c = ch & 3;
            int sw = c ^ (row & 3) ^ ((row >> 2) & 3);
            long gr = bm + row;
            int k = k0 + c * 8;
            bf16x8 w = (bf16x8){0, 0, 0, 0, 0, 0, 0, 0};
            if (gr < M) w = *(const bf16x8*)(A + (size_t)(k >> 4) * NN * GF + gr * GF + (k & 15));
            *(bf16x8*)(&As[row * BK + sw * 8]) = w;
        }
        __syncthreads();

        bf16x8 a[2];
        #pragma unroll
        for (int mi = 0; mi < 2; mi++) {
            int row = wr * 32 + mi * 16 + l15;
            int sw = g ^ (row & 3) ^ ((row >> 2) & 3);
            a[mi] = *(const bf16x8*)(&As[row * BK + sw * 8]);
        }
        #pragma unroll
        for (int ni = 0; ni < 4; ni++) {
            int row = ni * 16 + l15;
            int sw = g ^ (row & 3) ^ ((row >> 2) & 3);
            bf16x8 b = *(const bf16x8*)(&Bs[row * BK + sw * 8]);
            #pragma unroll
            for (int mi = 0; mi < 2; mi++)
                acc[mi][ni] = __builtin_amdgcn_mfma_f32_16x16x32_bf16(a[mi], b, acc[mi][ni], 0, 0, 0);
        }
        __syncthreads();
    }

    #pragma unroll
    for (int mi = 0; mi < 2; mi++) {
        long gr0 = bm + wr * 32 + mi * 16 + l4 * 4;
        #pragma unroll
        for (int ni = 0; ni < 4; ni++) {
            int gc = ni * 16 + l15;
            if (gc >= NC) continue;
            #pragma unroll
            for (int q = 0; q < 4; q++) {
                long gr = gr0 + q;
                if (gr < M) C[gr * NC + gc] = f2bf(acc[mi][ni][q]);
            }
        }
    }
}

// ---------------- group-blocked aggregation ----------------
// Block = 512 thr = 128 nodes (4-lane cluster per node). Stage edges+weights in LDS once,
// then 16 group phases; per phase gathers hit one 3.2MB plane (L2-resident).
__global__ __launch_bounds__(512)
void aggB_kernel(const unsigned short* __restrict__ tg, const int* __restrict__ row_ptr,
                 const int* __restrict__ csr, const float* __restrict__ dis,
                 const float* __restrict__ bias, unsigned short* __restrict__ outg, int n) {
    __shared__ int colsL[ECAP];
    __shared__ float wL[ECAP];
    __shared__ int rp[NPB + 1];

    const int tid = threadIdx.x;
    const int node0 = blockIdx.x * NPB;
    for (int i = tid; i <= NPB; i += 512) rp[i] = row_ptr[min(node0 + i, n)];
    __syncthreads();
    const int base = rp[0];

    const int cl = tid >> 2;          // node within block
    const int fl4 = (tid & 3) * 4;    // feature quad within group
    const int node = node0 + cl;
    const bool valid = node < n;
    int lo = rp[cl], hi = rp[cl + 1];
    float d = valid ? dis[node] : 0.f;

    // stage this node's edges
    for (int e = lo + (tid & 3); e < hi; e += 4) {
        int idx = e - base;
        if (idx < ECAP) {
            int c = csr[e];
            colsL[idx] = c;
            wL[idx] = d * dis[c];
        }
    }
    __syncthreads();

    const float d2 = d * d;
    #pragma unroll 1
    for (int g = 0; g < GB; g++) {
        const unsigned short* pl = tg + (size_t)g * NN * GF;
        if (valid) {
            u16x4 sv = *(const u16x4*)(pl + (size_t)node * GF + fl4);
            float a0 = bf2f(sv[0]) * d2, a1 = bf2f(sv[1]) * d2;
            float a2 = bf2f(sv[2]) * d2, a3 = bf2f(sv[3]) * d2;
            int e = lo;
            for (; e + 1 < hi; e += 2) {
                int i0 = e - base;
                int c0, c1; float w0, w1;
                if (i0 + 1 < ECAP) {
                    c0 = colsL[i0]; w0 = wL[i0];
                    c1 = colsL[i0 + 1]; w1 = wL[i0 + 1];
                } else {
                    c0 = csr[e]; w0 = d * dis[c0];
                    c1 = csr[e + 1]; w1 = d * dis[c1];
                }
                u16x4 v0 = *(const u16x4*)(pl + (size_t)c0 * GF + fl4);
                u16x4 v1 = *(const u16x4*)(pl + (size_t)c1 * GF + fl4);
                a0 += bf2f(v0[0]) * w0 + bf2f(v1[0]) * w1;
                a1 += bf2f(v0[1]) * w0 + bf2f(v1[1]) * w1;
                a2 += bf2f(v0[2]) * w0 + bf2f(v1[2]) * w1;
                a3 += bf2f(v0[3]) * w0 + bf2f(v1[3]) * w1;
            }
            if (e < hi) {
                int i0 = e - base;
                int c0; float w0;
                if (i0 < ECAP) { c0 = colsL[i0]; w0 = wL[i0]; }
                else { c0 = csr[e]; w0 = d * dis[c0]; }
                u16x4 v0 = *(const u16x4*)(pl + (size_t)c0 * GF + fl4);
                a0 += bf2f(v0[0]) * w0; a1 += bf2f(v0[1]) * w0;
                a2 += bf2f(v0[2]) * w0; a3 += bf2f(v0[3]) * w0;
            }
            const int f0 = g * GF + fl4;
            u16x4 o;
            o[0] = f2bf(fmaxf(a0 + bias[f0 + 0], 0.f));
            o[1] = f2bf(fmaxf(a1 + bias[f0 + 1], 0.f));
            o[2] = f2bf(fmaxf(a2 + bias[f0 + 2], 0.f));
            o[3] = f2bf(fmaxf(a3 + bias[f0 + 3], 0.f));
            union { u16x4 v; unsigned long long u; } cv; cv.v = o;
            __builtin_nontemporal_store(cv.u,
                (unsigned long long*)(outg + (size_t)g * NN * GF + (size_t)node * GF + fl4));
        }
    }
}

// agg40: t2p rows are 40 bf16 (80B). 8 groups of 8 lanes; lanes with f0<40 gather.
__global__ void agg40_kernel(const unsigned short* __restrict__ t, const int* __restrict__ row_ptr,
                             const int* __restrict__ csr, const float* __restrict__ dis,
                             const float* __restrict__ bias, float* __restrict__ out, int n) {
    const int wid = threadIdx.x >> 6, lane = threadIdx.x & 63;
    const int node = blockIdx.x * 4 + wid;
    if (node >= n) return;
    const int g = lane >> 3;
    const int f0 = (lane & 7) * 8;
    const bool act = f0 < NC;
    const float d = dis[node];
    float a[8];
    #pragma unroll
    for (int j = 0; j < 8; j++) a[j] = 0.f;
    const int lo = row_ptr[node], hi = row_ptr[node + 1];
    if (act) {
        if (g == 0) {
            u16x8 sv = *(const u16x8*)(t + (long)node * NC + f0);
            float d2 = d * d;
            #pragma unroll
            for (int j = 0; j < 8; j++) a[j] = bf2f(sv[j]) * d2;
        }
        int ee = lo + g;
        for (; ee + 8 < hi; ee += 16) {
            int c0 = csr[ee], c1 = csr[ee + 8];
            float w0 = d * dis[c0], w1 = d * dis[c1];
            u16x8 v0 = *(const u16x8*)(t + (long)c0 * NC + f0);
            u16x8 v1 = *(const u16x8*)(t + (long)c1 * NC + f0);
            #pragma unroll
            for (int j = 0; j < 8; j++)
                a[j] += bf2f(v0[j]) * w0 + bf2f(v1[j]) * w1;
        }
        if (ee < hi) {
            int c0 = csr[ee];
            float w0 = d * dis[c0];
            u16x8 v0 = *(const u16x8*)(t + (long)c0 * NC + f0);
            #pragma unroll
            for (int j = 0; j < 8; j++) a[j] += bf2f(v0[j]) * w0;
        }
    }
    #pragma unroll
    for (int s = 8; s < 64; s <<= 1)
        #pragma unroll
        for (int j = 0; j < 8; j++) a[j] += __shfl_xor(a[j], s);
    if (g == 0 && act) {
        float4 o0, o1;
        o0.x = a[0] + bias[f0 + 0]; o0.y = a[1] + bias[f0 + 1];
        o0.z = a[2] + bias[f0 + 2]; o0.w = a[3] + bias[f0 + 3];
        o1.x = a[4] + bias[f0 + 4]; o1.y = a[5] + bias[f0 + 5];
        o1.z = a[6] + bias[f0 + 6]; o1.w = a[7] + bias[f0 + 7];
        float* dst = out + (long)node * NC + f0;
        *(float4*)dst = o0;
        *(float4*)(dst + 4) = o1;
    }
}

// ---------------- launch ----------------

extern "C" void kernel_launch(void* const* d_in, const int* in_sizes, int n_in,
                              void* d_out, int out_size, void* d_ws, size_t ws_size,
                              hipStream_t stream) {
    const float* x     = (const float*)d_in[0];
    const int*   ei    = (const int*)d_in[1];
    const float* W_mlp = (const float*)d_in[2];
    const float* b_mlp = (const float*)d_in[3];
    const float* W1    = (const float*)d_in[4];
    const float* b1    = (const float*)d_in[5];
    const float* W2    = (const float*)d_in[6];
    const float* b2    = (const float*)d_in[7];
    float* out = (float*)d_out;

    // workspace layout (float units)
    float* ws = (float*)d_ws;
    size_t off = 0;
    float*    dis     = ws + off; off += 100096;
    int*      row_cnt = (int*)(ws + off); off += 100096;
    int*      row_ptr = (int*)(ws + off); off += 100096;
    int*      bsum    = (int*)(ws + off); off += 512;
    int*      boff    = (int*)(ws + off); off += 512;
    unsigned char* rpart8 = (unsigned char*)(ws + off); off += (size_t)PARTS * NPAD / 4;
    unsigned char* cpart8 = (unsigned char*)(ws + off); off += (size_t)PARTS * NPAD / 4;
    unsigned* rbase   = (unsigned*)(ws + off); off += (size_t)PARTS * NPAD;
    int*      csr     = (int*)(ws + off); off += (size_t)NE;
    unsigned short* WTm = (unsigned short*)(ws + off); off += (NH * NF) / 2;
    unsigned short* W1T = (unsigned short*)(ws + off); off += (NH * NH) / 2;
    unsigned short* W2T = (unsigned short*)(ws + off); off += (64 * NH) / 2;
    unsigned short* t1  = (unsigned short*)(ws + off); off += (size_t)NN * NH / 2;  // blocked [16][NN][16]
    unsigned short* h1  = (unsigned short*)(ws + off); off += (size_t)NN * NH / 2;  // blocked [16][NN][16]
    unsigned short* t2p = (unsigned short*)(ws + off); off += ((size_t)NN * NC + 8) / 2;
    (void)ws_size;

    dim3 gh(NCH, PARTS, 2);
    hist2_kernel<<<gh, 512, 0, stream>>>(ei, rpart8, cpart8);
    reduce_kernel<<<NBLK, 256, 0, stream>>>(rpart8, cpart8, row_cnt, dis, bsum);
    scanb_kernel<<<1, 512, 0, stream>>>(bsum, boff);
    rstart2_kernel<<<NBLK, 256, 0, stream>>>(rpart8, row_cnt, boff, row_ptr, rbase);
    dim3 gf(NCH, PARTS);
    fill2d_kernel<<<gf, 512, 0, stream>>>(ei, rbase, csr);

    wtrans_all<<<(NH * NF + NH * NH + 64 * NH + 255) / 256, 256, 0, stream>>>(
        W_mlp, W1, W2, WTm, W1T, W2T);

    const int mb = (NN + 127) / 128;  // 782
    // t1 (blocked) = (relu(x@Wm+b)) @ W1
    gemm12_kernel<<<mb, 512, 0, stream>>>(x, WTm, b_mlp, W1T, t1, NN);
    // h1 (blocked) = relu(agg(t1) + b1) — group-phased, L2-resident planes
    aggB_kernel<<<(NN + NPB - 1) / NPB, 512, 0, stream>>>(t1, row_ptr, csr, dis, b1, h1, NN);
    // t2p = h1 @ W2 (40-wide rows)
    gemm3_kernel<<<mb, 256, 0, stream>>>(h1, W2T, t2p, NN);
    // out = agg(t2p) + b2
    agg40_kernel<<<(NN + 3) / 4, 256, 0, stream>>>(t2p, row_ptr, csr, dis, b2, out, NN);
}

// Round 11
// 582.365 us; speedup vs baseline: 1.5329x; 1.5329x over previous
//
#include <hip/hip_runtime.h>

// GCNPre: N=100000 nodes, E=3200000 edges, F=512, H=256, C=40.
#define NN 100000
#define NE 3200000
#define NF 512
#define NH 256
#define NC 40

// CSR-build partitioning (round-8 structure: 256+ blocks, u8 partials).
#define CH 32768
#define NCH 4
#define NPAD (NCH * CH)              // 131072
#define PARTS 64
#define SLICE ((NE + PARTS - 1) / PARTS)   // 50000
#define NBLK ((NN + 255) / 256)      // 391

typedef __attribute__((ext_vector_type(8))) short bf16x8;
typedef __attribute__((ext_vector_type(4))) float f32x4;
typedef __attribute__((ext_vector_type(4))) unsigned short u16x4;
typedef __attribute__((ext_vector_type(8))) unsigned short u16x8;

__device__ inline unsigned short f2bf(float f) {
    union { float f; unsigned u; } v; v.f = f;
    unsigned r = v.u + 0x7fffu + ((v.u >> 16) & 1u);
    return (unsigned short)(r >> 16);
}
__device__ inline float bf2f(unsigned short s) {
    union { unsigned u; float f; } v; v.u = ((unsigned)s) << 16;
    return v.f;
}

// ---------------- CSR build (no global atomics) ----------------

__global__ __launch_bounds__(512) void hist2_kernel(const int* __restrict__ ei,
                                                    unsigned char* __restrict__ rpart8,
                                                    unsigned char* __restrict__ cpart8) {
    __shared__ unsigned h[CH / 2];   // u16-packed counters, 64KB
    const int chunk = blockIdx.x, part = blockIdx.y, which = blockIdx.z;
    const int* src = which ? (ei + NE) : ei;
    unsigned char* outp = which ? cpart8 : rpart8;
    const int lo = chunk * CH;
    for (int i = threadIdx.x; i < CH / 2; i += 512) h[i] = 0;
    __syncthreads();
    const int e1 = min((part + 1) * SLICE, NE);
    for (int e = part * SLICE + threadIdx.x; e < e1; e += 512) {
        unsigned v = (unsigned)(src[e] - lo);
        if (v < CH) atomicAdd(&h[v >> 1], 1u << ((v & 1) << 4));
    }
    __syncthreads();
    unsigned char* dst = outp + (size_t)part * NPAD + lo;
    for (int i = threadIdx.x; i < CH; i += 512)
        dst[i] = (unsigned char)((h[i >> 1] >> ((i & 1) << 4)) & 0xffu);
}

__global__ __launch_bounds__(256) void reduce_kernel(const unsigned char* __restrict__ rpart8,
                                                     const unsigned char* __restrict__ cpart8,
                                                     int* __restrict__ row_cnt, float* __restrict__ dis,
                                                     int* __restrict__ bsum) {
    __shared__ int s[256];
    const int tid = threadIdx.x;
    const int v = blockIdx.x * 256 + tid;
    unsigned rs = 0, cs = 0;
    if (v < NN) {
        #pragma unroll 1
        for (int p = 0; p < PARTS; p++) {
            rs += rpart8[(size_t)p * NPAD + v];
            cs += cpart8[(size_t)p * NPAD + v];
        }
        row_cnt[v] = (int)rs;
        dis[v] = rsqrtf((float)cs + 1.0f);
    }
    s[tid] = (int)rs;
    __syncthreads();
    #pragma unroll
    for (int o = 128; o > 0; o >>= 1) {
        if (tid < o) s[tid] += s[tid + o];
        __syncthreads();
    }
    if (tid == 0) bsum[blockIdx.x] = s[0];
}

__global__ __launch_bounds__(512) void scanb_kernel(const int* __restrict__ bsum,
                                                    int* __restrict__ boff) {
    __shared__ int s[512];
    const int t = threadIdx.x;
    int v = (t < NBLK) ? bsum[t] : 0;
    s[t] = v;
    __syncthreads();
    #pragma unroll
    for (int o = 1; o < 512; o <<= 1) {
        int u = (t >= o) ? s[t - o] : 0;
        __syncthreads();
        s[t] += u;
        __syncthreads();
    }
    if (t < NBLK) boff[t] = s[t] - v;   // exclusive
}

__global__ __launch_bounds__(256) void rstart2_kernel(const unsigned char* __restrict__ rpart8,
                                                      const int* __restrict__ row_cnt,
                                                      const int* __restrict__ boff,
                                                      int* __restrict__ row_ptr,
                                                      unsigned* __restrict__ rbase) {
    __shared__ int s[256];
    const int tid = threadIdx.x;
    const int v = blockIdx.x * 256 + tid;
    int cnt = (v < NN) ? row_cnt[v] : 0;
    s[tid] = cnt;
    __syncthreads();
    #pragma unroll
    for (int o = 1; o < 256; o <<= 1) {
        int u = (tid >= o) ? s[tid - o] : 0;
        __syncthreads();
        s[tid] += u;
        __syncthreads();
    }
    if (v < NN) {
        unsigned run = (unsigned)(boff[blockIdx.x] + s[tid] - cnt);
        row_ptr[v] = (int)run;
        #pragma unroll 1
        for (int p = 0; p < PARTS; p++) {
            size_t i = (size_t)p * NPAD + v;
            rbase[i] = run;
            run += rpart8[i];
        }
    }
    if (v == NN) row_ptr[NN] = NE;
}

// Fill packed CSR records {col, w} with packed-u16 LDS cursors (r8 form).
__global__ __launch_bounds__(512) void fill2d_kernel(const int* __restrict__ ei,
                                                     const unsigned* __restrict__ rbase,
                                                     const float* __restrict__ dis,
                                                     int2* __restrict__ csr) {
    __shared__ unsigned cur[CH / 2];
    const int chunk = blockIdx.x, part = blockIdx.y;
    const int lo = chunk * CH;
    for (int i = threadIdx.x; i < CH / 2; i += 512) cur[i] = 0;
    __syncthreads();
    const unsigned* base = rbase + (size_t)part * NPAD + lo;
    const int e1 = min((part + 1) * SLICE, NE);
    for (int e = part * SLICE + threadIdx.x; e < e1; e += 512) {
        int r = ei[e];
        unsigned rr = (unsigned)(r - lo);
        if (rr < CH) {
            int c = ei[NE + e];
            unsigned sh = (rr & 1) << 4;
            unsigned old = atomicAdd(&cur[rr >> 1], 1u << sh);
            unsigned p = (old >> sh) & 0xffffu;
            unsigned idx = base[rr] + p;
            int2 rec;
            rec.x = c;
            rec.y = __float_as_int(dis[r] * dis[c]);
            csr[idx] = rec;
        }
    }
}

// ---------------- weight transpose + bf16 cast (fused, plain layout) ----------------
__global__ void wtrans_all(const float* __restrict__ Wm, const float* __restrict__ W1,
                           const float* __restrict__ W2, unsigned short* __restrict__ WTm,
                           unsigned short* __restrict__ W1T, unsigned short* __restrict__ W2T) {
    int t = blockIdx.x * 256 + threadIdx.x;
    if (t < NH * NF) {                   // WTm[n][k] = Wm[k][n]
        int n = t / NF, k = t % NF;
        WTm[t] = f2bf(Wm[(long)k * NH + n]);
        return;
    }
    t -= NH * NF;
    if (t < NH * NH) {                   // W1T[n][k] = W1[k][n]
        int n = t / NH, k = t % NH;
        W1T[t] = f2bf(W1[(long)k * NH + n]);
        return;
    }
    t -= NH * NH;
    if (t < 64 * NH) {                   // W2T[n][k] = W2[k][n], padded to 64 rows
        int n = t / NH, k = t % NH;
        W2T[t] = (n < NC) ? f2bf(W2[(long)k * NC + n]) : (unsigned short)0;
    }
}

// ---------------- fused GEMM1+GEMM2 (r8 form) ----------------
__global__ __launch_bounds__(512)
void gemm12_kernel(const float* __restrict__ x, const unsigned short* __restrict__ WTm,
                   const float* __restrict__ bmlp, const unsigned short* __restrict__ W1T,
                   unsigned short* __restrict__ t1, int M) {
    __shared__ char smem[81920];
    short* h0s = (short*)smem;                 // [128][256] bf16, chunk-swizzled (64KB)
    short* As  = (short*)smem;                 // stage1 A [128][32]
    short* Bs  = (short*)(smem + 8192);        // stage1 B [256][32]
    short* Bs2 = (short*)(smem + 65536);       // stage2 B [256][32]

    const int tid = threadIdx.x;
    const int lane = tid & 63;
    const int wid = tid >> 6;
    const int wr = wid >> 1;
    const int wc = wid & 1;
    const long bm = (long)blockIdx.x * 128;
    const int l15 = lane & 15, g = lane >> 4, l4 = lane >> 4;

    f32x4 acc[2][8];
    #pragma unroll
    for (int i = 0; i < 2; i++)
        #pragma unroll
        for (int j = 0; j < 8; j++) acc[i][j] = (f32x4){0.f, 0.f, 0.f, 0.f};

    for (int k0 = 0; k0 < NF; k0 += 32) {
        {
            int ch = tid;
            int row = ch >> 2, c = ch & 3;
            int sw = c ^ (row & 3) ^ ((row >> 2) & 3);
            long gr = bm + row;
            bf16x8 w = (bf16x8){0, 0, 0, 0, 0, 0, 0, 0};
            if (gr < M) {
                float4 v0 = *(const float4*)(x + gr * NF + k0 + c * 8);
                float4 v1 = *(const float4*)(x + gr * NF + k0 + c * 8 + 4);
                w[0] = (short)f2bf(v0.x); w[1] = (short)f2bf(v0.y);
                w[2] = (short)f2bf(v0.z); w[3] = (short)f2bf(v0.w);
                w[4] = (short)f2bf(v1.x); w[5] = (short)f2bf(v1.y);
                w[6] = (short)f2bf(v1.z); w[7] = (short)f2bf(v1.w);
            }
            *(bf16x8*)(As + row * 32 + sw * 8) = w;
        }
        #pragma unroll
        for (int i = 0; i < 2; i++) {
            int ch = tid + i * 512;
            int row = ch >> 2, c = ch & 3;
            int sw = c ^ (row & 3) ^ ((row >> 2) & 3);
            bf16x8 w = *(const bf16x8*)(WTm + (long)row * NF + k0 + c * 8);
            *(bf16x8*)(Bs + row * 32 + sw * 8) = w;
        }
        __syncthreads();

        bf16x8 a[2];
        #pragma unroll
        for (int mi = 0; mi < 2; mi++) {
            int row = wr * 32 + mi * 16 + l15;
            int sw = g ^ (row & 3) ^ ((row >> 2) & 3);
            a[mi] = *(const bf16x8*)(As + row * 32 + sw * 8);
        }
        #pragma unroll
        for (int ni = 0; ni < 8; ni++) {
            int row = wc * 128 + ni * 16 + l15;
            int sw = g ^ (row & 3) ^ ((row >> 2) & 3);
            bf16x8 b = *(const bf16x8*)(Bs + row * 32 + sw * 8);
            #pragma unroll
            for (int mi = 0; mi < 2; mi++)
                acc[mi][ni] = __builtin_amdgcn_mfma_f32_16x16x32_bf16(a[mi], b, acc[mi][ni], 0, 0, 0);
        }
        __syncthreads();
    }

    #pragma unroll
    for (int mi = 0; mi < 2; mi++) {
        int r0 = wr * 32 + mi * 16 + l4 * 4;
        #pragma unroll
        for (int ni = 0; ni < 8; ni++) {
            int gc = wc * 128 + ni * 16 + l15;
            float bv = bmlp[gc];
            int cc = gc >> 3, c7 = gc & 7;
            #pragma unroll
            for (int q = 0; q < 4; q++) {
                int row = r0 + q;
                float v = fmaxf(acc[mi][ni][q] + bv, 0.f);
                h0s[row * 256 + ((cc ^ (row & 7)) << 3) + c7] = (short)f2bf(v);
            }
        }
    }

    #pragma unroll
    for (int i = 0; i < 2; i++)
        #pragma unroll
        for (int j = 0; j < 8; j++) acc[i][j] = (f32x4){0.f, 0.f, 0.f, 0.f};

    for (int k2 = 0; k2 < NH; k2 += 32) {
        #pragma unroll
        for (int i = 0; i < 2; i++) {
            int ch = tid + i * 512;
            int row = ch >> 2, c = ch & 3;
            int sw = c ^ (row & 3) ^ ((row >> 2) & 3);
            bf16x8 w = *(const bf16x8*)(W1T + (long)row * NH + k2 + c * 8);
            *(bf16x8*)(Bs2 + row * 32 + sw * 8) = w;
        }
        __syncthreads();

        bf16x8 a[2];
        #pragma unroll
        for (int mi = 0; mi < 2; mi++) {
            int row = wr * 32 + mi * 16 + l15;
            int cc = (k2 >> 3) + g;
            a[mi] = *(const bf16x8*)(h0s + row * 256 + ((cc ^ (row & 7)) << 3));
        }
        #pragma unroll
        for (int ni = 0; ni < 8; ni++) {
            int row = wc * 128 + ni * 16 + l15;
            int sw = g ^ (row & 3) ^ ((row >> 2) & 3);
            bf16x8 b = *(const bf16x8*)(Bs2 + row * 32 + sw * 8);
            #pragma unroll
            for (int mi = 0; mi < 2; mi++)
                acc[mi][ni] = __builtin_amdgcn_mfma_f32_16x16x32_bf16(a[mi], b, acc[mi][ni], 0, 0, 0);
        }
        __syncthreads();
    }

    #pragma unroll
    for (int mi = 0; mi < 2; mi++) {
        long gr0 = bm + wr * 32 + mi * 16 + l4 * 4;
        #pragma unroll
        for (int ni = 0; ni < 8; ni++) {
            int gc = wc * 128 + ni * 16 + l15;
            #pragma unroll
            for (int q = 0; q < 4; q++) {
                long gr = gr0 + q;
                if (gr < M) t1[gr * NH + gc] = f2bf(acc[mi][ni][q]);
            }
        }
    }
}

// ---------------- GEMM3 (h1 @ W2 -> split planes t2A[NN][32], t2B[NN][8]) ----------------
__global__ __launch_bounds__(256)
void gemm3_kernel(const unsigned short* __restrict__ A, const unsigned short* __restrict__ W2T,
                  unsigned short* __restrict__ t2A, unsigned short* __restrict__ t2B, int M) {
    constexpr int BM = 128, BK = 32;
    __shared__ short As[BM * BK];
    __shared__ short Bs[64 * BK];

    const int tid = threadIdx.x;
    const int lane = tid & 63;
    const int wid = tid >> 6;
    const int wr = wid;
    const long bm = (long)blockIdx.x * BM;
    const int l15 = lane & 15, g = lane >> 4, l4 = lane >> 4;

    f32x4 acc[2][4];
    #pragma unroll
    for (int i = 0; i < 2; i++)
        #pragma unroll
        for (int j = 0; j < 4; j++) acc[i][j] = (f32x4){0.f, 0.f, 0.f, 0.f};

    for (int k0 = 0; k0 < NH; k0 += BK) {
        #pragma unroll
        for (int i = 0; i < 2; i++) {
            int ch = tid + i * 256;
            int row = ch >> 2, c = ch & 3;
            int sw = c ^ (row & 3) ^ ((row >> 2) & 3);
            long gr = bm + row;
            bf16x8 w = (bf16x8){0, 0, 0, 0, 0, 0, 0, 0};
            if (gr < M) w = *(const bf16x8*)(A + gr * NH + k0 + c * 8);
            *(bf16x8*)(&As[row * BK + sw * 8]) = w;
        }
        {
            int ch = tid;
            int row = ch >> 2, c = ch & 3;
            int sw = c ^ (row & 3) ^ ((row >> 2) & 3);
            bf16x8 w = *(const bf16x8*)(W2T + (long)row * NH + k0 + c * 8);
            *(bf16x8*)(&Bs[row * BK + sw * 8]) = w;
        }
        __syncthreads();

        bf16x8 a[2];
        #pragma unroll
        for (int mi = 0; mi < 2; mi++) {
            int row = wr * 32 + mi * 16 + l15;
            int sw = g ^ (row & 3) ^ ((row >> 2) & 3);
            a[mi] = *(const bf16x8*)(&As[row * BK + sw * 8]);
        }
        #pragma unroll
        for (int ni = 0; ni < 4; ni++) {
            int row = ni * 16 + l15;
            int sw = g ^ (row & 3) ^ ((row >> 2) & 3);
            bf16x8 b = *(const bf16x8*)(&Bs[row * BK + sw * 8]);
            #pragma unroll
            for (int mi = 0; mi < 2; mi++)
                acc[mi][ni] = __builtin_amdgcn_mfma_f32_16x16x32_bf16(a[mi], b, acc[mi][ni], 0, 0, 0);
        }
        __syncthreads();
    }

    #pragma unroll
    for (int mi = 0; mi < 2; mi++) {
        long gr0 = bm + wr * 32 + mi * 16 + l4 * 4;
        #pragma unroll
        for (int ni = 0; ni < 4; ni++) {
            int gc = ni * 16 + l15;
            if (gc >= NC) continue;
            #pragma unroll
            for (int q = 0; q < 4; q++) {
                long gr = gr0 + q;
                if (gr >= M) continue;
                unsigned short v = f2bf(acc[mi][ni][q]);
                if (gc < 32) t2A[gr * 32 + gc] = v;
                else         t2B[gr * 8 + (gc - 32)] = v;
            }
        }
    }
}

// ---------------- aggregation (gather SpMM, bf16 payload, int2 edge records) ----------------
__global__ void agg256_kernel(const unsigned short* __restrict__ t, const int* __restrict__ row_ptr,
                              const int2* __restrict__ csr, const float* __restrict__ dis,
                              const float* __restrict__ bias, unsigned short* __restrict__ out, int n) {
    const int wid = threadIdx.x >> 6, lane = threadIdx.x & 63;
    const int node = blockIdx.x * 4 + wid;
    if (node >= n) return;
    const int half = lane >> 5;
    const int f0 = (lane & 31) * 8;
    const float d = dis[node];
    float a[8];
    if (half == 0) {
        u16x8 sv = *(const u16x8*)(t + (long)node * NH + f0);
        float d2 = d * d;
        #pragma unroll
        for (int j = 0; j < 8; j++) a[j] = bf2f(sv[j]) * d2;
    } else {
        #pragma unroll
        for (int j = 0; j < 8; j++) a[j] = 0.f;
    }
    const int lo = row_ptr[node], hi = row_ptr[node + 1];
    int ee = lo + half;
    for (; ee + 6 < hi; ee += 8) {
        int2 r0 = csr[ee];
        int2 r1 = csr[ee + 2];
        int2 r2 = csr[ee + 4];
        int2 r3 = csr[ee + 6];
        u16x8 v0 = *(const u16x8*)(t + (long)r0.x * NH + f0);
        u16x8 v1 = *(const u16x8*)(t + (long)r1.x * NH + f0);
        u16x8 v2 = *(const u16x8*)(t + (long)r2.x * NH + f0);
        u16x8 v3 = *(const u16x8*)(t + (long)r3.x * NH + f0);
        float w0 = __int_as_float(r0.y), w1 = __int_as_float(r1.y);
        float w2 = __int_as_float(r2.y), w3 = __int_as_float(r3.y);
        #pragma unroll
        for (int j = 0; j < 8; j++)
            a[j] += (bf2f(v0[j]) * w0 + bf2f(v1[j]) * w1) + (bf2f(v2[j]) * w2 + bf2f(v3[j]) * w3);
    }
    for (; ee + 2 < hi; ee += 4) {
        int2 r0 = csr[ee];
        int2 r1 = csr[ee + 2];
        u16x8 v0 = *(const u16x8*)(t + (long)r0.x * NH + f0);
        u16x8 v1 = *(const u16x8*)(t + (long)r1.x * NH + f0);
        float w0 = __int_as_float(r0.y), w1 = __int_as_float(r1.y);
        #pragma unroll
        for (int j = 0; j < 8; j++)
            a[j] += bf2f(v0[j]) * w0 + bf2f(v1[j]) * w1;
    }
    if (ee < hi) {
        int2 r0 = csr[ee];
        u16x8 v0 = *(const u16x8*)(t + (long)r0.x * NH + f0);
        float w0 = __int_as_float(r0.y);
        #pragma unroll
        for (int j = 0; j < 8; j++) a[j] += bf2f(v0[j]) * w0;
    }
    #pragma unroll
    for (int j = 0; j < 8; j++) a[j] += __shfl_xor(a[j], 32);
    if (half == 0) {
        u16x8 o;
        #pragma unroll
        for (int j = 0; j < 8; j++)
            o[j] = f2bf(fmaxf(a[j] + bias[f0 + j], 0.f));
        *(u16x8*)(out + (long)node * NH + f0) = o;
    }
}

// agg40: split planes. Lanes s=0..3 of each 8-lane group gather 16B from t2A (64B-aligned
// rows, 1 line/edge fully consumed); lane s=4 gathers 16B from t2B (1.6MB, L2-resident).
__global__ void agg40_kernel(const unsigned short* __restrict__ tA, const unsigned short* __restrict__ tB,
                             const int* __restrict__ row_ptr, const int2* __restrict__ csr,
                             const float* __restrict__ dis, const float* __restrict__ bias,
                             float* __restrict__ out, int n) {
    const int wid = threadIdx.x >> 6, lane = threadIdx.x & 63;
    const int node = blockIdx.x * 4 + wid;
    if (node >= n) return;
    const int g = lane >> 3;
    const int s = lane & 7;
    const int f0 = s * 8;
    const bool act = f0 < NC;                 // s < 5
    const unsigned short* gp = (s < 4) ? tA : tB;
    const int ss = (s < 4) ? 5 : 3;           // row length shift (32 or 8 elems)
    const int fo = (s < 4) ? f0 : 0;          // intra-row elem offset
    const float d = dis[node];
    float a[8];
    #pragma unroll
    for (int j = 0; j < 8; j++) a[j] = 0.f;
    const int lo = row_ptr[node], hi = row_ptr[node + 1];
    if (act) {
        if (g == 0) {
            u16x8 sv = *(const u16x8*)(gp + (((size_t)node) << ss) + fo);
            float d2 = d * d;
            #pragma unroll
            for (int j = 0; j < 8; j++) a[j] = bf2f(sv[j]) * d2;
        }
        int ee = lo + g;
        for (; ee + 8 < hi; ee += 16) {
            int2 r0 = csr[ee];
            int2 r1 = csr[ee + 8];
            u16x8 v0 = *(const u16x8*)(gp + (((size_t)r0.x) << ss) + fo);
            u16x8 v1 = *(const u16x8*)(gp + (((size_t)r1.x) << ss) + fo);
            float w0 = __int_as_float(r0.y), w1 = __int_as_float(r1.y);
            #pragma unroll
            for (int j = 0; j < 8; j++)
                a[j] += bf2f(v0[j]) * w0 + bf2f(v1[j]) * w1;
        }
        if (ee < hi) {
            int2 r0 = csr[ee];
            u16x8 v0 = *(const u16x8*)(gp + (((size_t)r0.x) << ss) + fo);
            float w0 = __int_as_float(r0.y);
            #pragma unroll
            for (int j = 0; j < 8; j++) a[j] += bf2f(v0[j]) * w0;
        }
    }
    #pragma unroll
    for (int st = 8; st < 64; st <<= 1)
        #pragma unroll
        for (int j = 0; j < 8; j++) a[j] += __shfl_xor(a[j], st);
    if (g == 0 && act) {
        float4 o0, o1;
        o0.x = a[0] + bias[f0 + 0]; o0.y = a[1] + bias[f0 + 1];
        o0.z = a[2] + bias[f0 + 2]; o0.w = a[3] + bias[f0 + 3];
        o1.x = a[4] + bias[f0 + 4]; o1.y = a[5] + bias[f0 + 5];
        o1.z = a[6] + bias[f0 + 6]; o1.w = a[7] + bias[f0 + 7];
        float* dst = out + (long)node * NC + f0;
        *(float4*)dst = o0;
        *(float4*)(dst + 4) = o1;
    }
}

// ---------------- launch ----------------

extern "C" void kernel_launch(void* const* d_in, const int* in_sizes, int n_in,
                              void* d_out, int out_size, void* d_ws, size_t ws_size,
                              hipStream_t stream) {
    const float* x     = (const float*)d_in[0];
    const int*   ei    = (const int*)d_in[1];
    const float* W_mlp = (const float*)d_in[2];
    const float* b_mlp = (const float*)d_in[3];
    const float* W1    = (const float*)d_in[4];
    const float* b1    = (const float*)d_in[5];
    const float* W2    = (const float*)d_in[6];
    const float* b2    = (const float*)d_in[7];
    float* out = (float*)d_out;

    // workspace layout (float units)
    float* ws = (float*)d_ws;
    size_t off = 0;
    float*    dis     = ws + off; off += 100096;
    int*      row_cnt = (int*)(ws + off); off += 100096;
    int*      row_ptr = (int*)(ws + off); off += 100096;
    int*      bsum    = (int*)(ws + off); off += 512;
    int*      boff    = (int*)(ws + off); off += 512;
    unsigned char* rpart8 = (unsigned char*)(ws + off); off += (size_t)PARTS * NPAD / 4;
    unsigned char* cpart8 = (unsigned char*)(ws + off); off += (size_t)PARTS * NPAD / 4;
    unsigned* rbase   = (unsigned*)(ws + off); off += (size_t)PARTS * NPAD;
    int2*     csr     = (int2*)(ws + off); off += (size_t)NE * 2;
    unsigned short* WTm = (unsigned short*)(ws + off); off += (NH * NF) / 2;
    unsigned short* W1T = (unsigned short*)(ws + off); off += (NH * NH) / 2;
    unsigned short* W2T = (unsigned short*)(ws + off); off += (64 * NH) / 2;
    unsigned short* t1  = (unsigned short*)(ws + off); off += (size_t)NN * NH / 2;
    unsigned short* h1  = (unsigned short*)(ws + off); off += (size_t)NN * NH / 2;
    unsigned short* t2A = (unsigned short*)(ws + off); off += (size_t)NN * 32 / 2;
    unsigned short* t2B = (unsigned short*)(ws + off); off += (size_t)NN * 8 / 2;
    (void)ws_size;

    dim3 gh(NCH, PARTS, 2);
    hist2_kernel<<<gh, 512, 0, stream>>>(ei, rpart8, cpart8);
    reduce_kernel<<<NBLK, 256, 0, stream>>>(rpart8, cpart8, row_cnt, dis, bsum);
    scanb_kernel<<<1, 512, 0, stream>>>(bsum, boff);
    rstart2_kernel<<<NBLK, 256, 0, stream>>>(rpart8, row_cnt, boff, row_ptr, rbase);
    dim3 gf(NCH, PARTS);
    fill2d_kernel<<<gf, 512, 0, stream>>>(ei, rbase, dis, csr);

    wtrans_all<<<(NH * NF + NH * NH + 64 * NH + 255) / 256, 256, 0, stream>>>(
        W_mlp, W1, W2, WTm, W1T, W2T);

    const int mb = (NN + 127) / 128;  // 782
    // t1 = (relu(x@Wm+b)) @ W1, fused (h0 stays in LDS)
    gemm12_kernel<<<mb, 512, 0, stream>>>(x, WTm, b_mlp, W1T, t1, NN);
    // h1 = relu(agg(t1) + b1)
    agg256_kernel<<<(NN + 3) / 4, 256, 0, stream>>>(t1, row_ptr, csr, dis, b1, h1, NN);
    // t2A/t2B = h1 @ W2 (split 32+8 planes)
    gemm3_kernel<<<mb, 256, 0, stream>>>(h1, W2T, t2A, t2B, NN);
    // out = agg(t2A,t2B) + b2
    agg40_kernel<<<(NN + 3) / 4, 256, 0, stream>>>(t2A, t2B, row_ptr, csr, dis, b2, out, NN);
}

// Round 12
// 574.505 us; speedup vs baseline: 1.5539x; 1.0137x over previous
//
#include <hip/hip_runtime.h>

// GCNPre: N=100000 nodes, E=3200000 edges, F=512, H=256, C=40.
#define NN 100000
#define NE 3200000
#define NF 512
#define NH 256
#define NC 40

// CSR-build partitioning.
#define CH 32768                     // fill chunk (u16 cursors, 64KB LDS, 256 blocks)
#define NCH 4
#define CH2 65536                    // hist chunk (u8 counters, 64KB LDS, 256 blocks)
#define NCH2 2
#define NPAD (NCH * CH)              // 131072
#define PARTS 64
#define SLICE ((NE + PARTS - 1) / PARTS)   // 50000
#define NBLK ((NN + 255) / 256)      // 391

typedef __attribute__((ext_vector_type(8))) short bf16x8;
typedef __attribute__((ext_vector_type(4))) float f32x4;
typedef __attribute__((ext_vector_type(4))) unsigned short u16x4;
typedef __attribute__((ext_vector_type(8))) unsigned short u16x8;

__device__ inline unsigned short f2bf(float f) {
    union { float f; unsigned u; } v; v.f = f;
    unsigned r = v.u + 0x7fffu + ((v.u >> 16) & 1u);
    return (unsigned short)(r >> 16);
}
__device__ inline float bf2f(unsigned short s) {
    union { unsigned u; float f; } v; v.u = ((unsigned)s) << 16;
    return v.f;
}

// ---------------- CSR build (no global atomics) ----------------
// Per-(chunk,slice,node) counts are Poisson(<=0.5): max ~8 << 255, u8 safe.
// Within-row offsets are bounded by row degree ~ Poisson(32): max ~70 << 255, u8 safe.

// blockIdx = (chunk2, part, which). u8-packed 64KB histogram over CH2 nodes.
__global__ __launch_bounds__(512) void hist2_kernel(const int* __restrict__ ei,
                                                    unsigned char* __restrict__ rpart8,
                                                    unsigned char* __restrict__ cpart8) {
    __shared__ unsigned h[CH2 / 4];   // u8-packed counters, 64KB
    const int chunk = blockIdx.x, part = blockIdx.y, which = blockIdx.z;
    const int* src = which ? (ei + NE) : ei;
    unsigned char* outp = which ? cpart8 : rpart8;
    const int lo = chunk * CH2;
    for (int i = threadIdx.x; i < CH2 / 4; i += 512) h[i] = 0;
    __syncthreads();
    const int e1 = min((part + 1) * SLICE, NE);
    for (int e = part * SLICE + threadIdx.x; e < e1; e += 512) {
        unsigned v = (unsigned)(src[e] - lo);
        if (v < CH2) atomicAdd(&h[v >> 2], 1u << ((v & 3) << 3));
    }
    __syncthreads();
    unsigned* dst = (unsigned*)(outp + (size_t)part * NPAD + lo);
    for (int i = threadIdx.x; i < CH2 / 4; i += 512) dst[i] = h[i];
}

__global__ __launch_bounds__(256) void reduce_kernel(const unsigned char* __restrict__ rpart8,
                                                     const unsigned char* __restrict__ cpart8,
                                                     int* __restrict__ row_cnt, float* __restrict__ dis,
                                                     int* __restrict__ bsum) {
    __shared__ int s[256];
    const int tid = threadIdx.x;
    const int v = blockIdx.x * 256 + tid;
    unsigned rs = 0, cs = 0;
    if (v < NN) {
        #pragma unroll 1
        for (int p = 0; p < PARTS; p++) {
            rs += rpart8[(size_t)p * NPAD + v];
            cs += cpart8[(size_t)p * NPAD + v];
        }
        row_cnt[v] = (int)rs;
        dis[v] = rsqrtf((float)cs + 1.0f);
    }
    s[tid] = (int)rs;
    __syncthreads();
    #pragma unroll
    for (int o = 128; o > 0; o >>= 1) {
        if (tid < o) s[tid] += s[tid + o];
        __syncthreads();
    }
    if (tid == 0) bsum[blockIdx.x] = s[0];
}

__global__ __launch_bounds__(512) void scanb_kernel(const int* __restrict__ bsum,
                                                    int* __restrict__ boff) {
    __shared__ int s[512];
    const int t = threadIdx.x;
    int v = (t < NBLK) ? bsum[t] : 0;
    s[t] = v;
    __syncthreads();
    #pragma unroll
    for (int o = 1; o < 512; o <<= 1) {
        int u = (t >= o) ? s[t - o] : 0;
        __syncthreads();
        s[t] += u;
        __syncthreads();
    }
    if (t < NBLK) boff[t] = s[t] - v;   // exclusive
}

// row_ptr[v] = boff + intra-block scan; rbase8[p][v] = within-row prefix over slices (u8).
__global__ __launch_bounds__(256) void rstart2_kernel(const unsigned char* __restrict__ rpart8,
                                                      const int* __restrict__ row_cnt,
                                                      const int* __restrict__ boff,
                                                      int* __restrict__ row_ptr,
                                                      unsigned char* __restrict__ rbase8) {
    __shared__ int s[256];
    const int tid = threadIdx.x;
    const int v = blockIdx.x * 256 + tid;
    int cnt = (v < NN) ? row_cnt[v] : 0;
    s[tid] = cnt;
    __syncthreads();
    #pragma unroll
    for (int o = 1; o < 256; o <<= 1) {
        int u = (tid >= o) ? s[tid - o] : 0;
        __syncthreads();
        s[tid] += u;
        __syncthreads();
    }
    if (v < NN) {
        row_ptr[v] = boff[blockIdx.x] + s[tid] - cnt;
        unsigned off = 0;
        #pragma unroll 1
        for (int p = 0; p < PARTS; p++) {
            size_t i = (size_t)p * NPAD + v;
            rbase8[i] = (unsigned char)off;
            off += rpart8[i];
        }
    }
    if (v == NN) row_ptr[NN] = NE;
}

// Fill packed CSR records {col, w}: idx = row_ptr[r] + rbase8[part][r] + LDS cursor.
__global__ __launch_bounds__(512) void fill2d_kernel(const int* __restrict__ ei,
                                                     const unsigned char* __restrict__ rbase8,
                                                     const int* __restrict__ row_ptr,
                                                     const float* __restrict__ dis,
                                                     int2* __restrict__ csr) {
    __shared__ unsigned cur[CH / 2];
    const int chunk = blockIdx.x, part = blockIdx.y;
    const int lo = chunk * CH;
    for (int i = threadIdx.x; i < CH / 2; i += 512) cur[i] = 0;
    __syncthreads();
    const unsigned char* base8 = rbase8 + (size_t)part * NPAD;
    const int e1 = min((part + 1) * SLICE, NE);
    for (int e = part * SLICE + threadIdx.x; e < e1; e += 512) {
        int r = ei[e];
        unsigned rr = (unsigned)(r - lo);
        if (rr < CH) {
            int c = ei[NE + e];
            unsigned sh = (rr & 1) << 4;
            unsigned old = atomicAdd(&cur[rr >> 1], 1u << sh);
            unsigned p = (old >> sh) & 0xffffu;
            unsigned idx = (unsigned)row_ptr[r] + base8[r] + p;
            int2 rec;
            rec.x = c;
            rec.y = __float_as_int(dis[r] * dis[c]);
            csr[idx] = rec;
        }
    }
}

// ---------------- weight transpose + bf16 cast (fused, plain layout) ----------------
__global__ void wtrans_all(const float* __restrict__ Wm, const float* __restrict__ W1,
                           const float* __restrict__ W2, unsigned short* __restrict__ WTm,
                           unsigned short* __restrict__ W1T, unsigned short* __restrict__ W2T) {
    int t = blockIdx.x * 256 + threadIdx.x;
    if (t < NH * NF) {                   // WTm[n][k] = Wm[k][n]
        int n = t / NF, k = t % NF;
        WTm[t] = f2bf(Wm[(long)k * NH + n]);
        return;
    }
    t -= NH * NF;
    if (t < NH * NH) {                   // W1T[n][k] = W1[k][n]
        int n = t / NH, k = t % NH;
        W1T[t] = f2bf(W1[(long)k * NH + n]);
        return;
    }
    t -= NH * NH;
    if (t < 64 * NH) {                   // W2T[n][k] = W2[k][n], padded to 64 rows
        int n = t / NH, k = t % NH;
        W2T[t] = (n < NC) ? f2bf(W2[(long)k * NC + n]) : (unsigned short)0;
    }
}

// ---------------- fused GEMM1+GEMM2 ----------------
__global__ __launch_bounds__(512)
void gemm12_kernel(const float* __restrict__ x, const unsigned short* __restrict__ WTm,
                   const float* __restrict__ bmlp, const unsigned short* __restrict__ W1T,
                   unsigned short* __restrict__ t1, int M) {
    __shared__ char smem[81920];
    short* h0s = (short*)smem;                 // [128][256] bf16, chunk-swizzled (64KB)
    short* As  = (short*)smem;                 // stage1 A [128][32]
    short* Bs  = (short*)(smem + 8192);        // stage1 B [256][32]
    short* Bs2 = (short*)(smem + 65536);       // stage2 B [256][32]

    const int tid = threadIdx.x;
    const int lane = tid & 63;
    const int wid = tid >> 6;
    const int wr = wid >> 1;
    const int wc = wid & 1;
    const long bm = (long)blockIdx.x * 128;
    const int l15 = lane & 15, g = lane >> 4, l4 = lane >> 4;

    f32x4 acc[2][8];
    #pragma unroll
    for (int i = 0; i < 2; i++)
        #pragma unroll
        for (int j = 0; j < 8; j++) acc[i][j] = (f32x4){0.f, 0.f, 0.f, 0.f};

    for (int k0 = 0; k0 < NF; k0 += 32) {
        {
            int ch = tid;
            int row = ch >> 2, c = ch & 3;
            int sw = c ^ (row & 3) ^ ((row >> 2) & 3);
            long gr = bm + row;
            bf16x8 w = (bf16x8){0, 0, 0, 0, 0, 0, 0, 0};
            if (gr < M) {
                float4 v0 = *(const float4*)(x + gr * NF + k0 + c * 8);
                float4 v1 = *(const float4*)(x + gr * NF + k0 + c * 8 + 4);
                w[0] = (short)f2bf(v0.x); w[1] = (short)f2bf(v0.y);
                w[2] = (short)f2bf(v0.z); w[3] = (short)f2bf(v0.w);
                w[4] = (short)f2bf(v1.x); w[5] = (short)f2bf(v1.y);
                w[6] = (short)f2bf(v1.z); w[7] = (short)f2bf(v1.w);
            }
            *(bf16x8*)(As + row * 32 + sw * 8) = w;
        }
        #pragma unroll
        for (int i = 0; i < 2; i++) {
            int ch = tid + i * 512;
            int row = ch >> 2, c = ch & 3;
            int sw = c ^ (row & 3) ^ ((row >> 2) & 3);
            bf16x8 w = *(const bf16x8*)(WTm + (long)row * NF + k0 + c * 8);
            *(bf16x8*)(Bs + row * 32 + sw * 8) = w;
        }
        __syncthreads();

        bf16x8 a[2];
        #pragma unroll
        for (int mi = 0; mi < 2; mi++) {
            int row = wr * 32 + mi * 16 + l15;
            int sw = g ^ (row & 3) ^ ((row >> 2) & 3);
            a[mi] = *(const bf16x8*)(As + row * 32 + sw * 8);
        }
        #pragma unroll
        for (int ni = 0; ni < 8; ni++) {
            int row = wc * 128 + ni * 16 + l15;
            int sw = g ^ (row & 3) ^ ((row >> 2) & 3);
            bf16x8 b = *(const bf16x8*)(Bs + row * 32 + sw * 8);
            #pragma unroll
            for (int mi = 0; mi < 2; mi++)
                acc[mi][ni] = __builtin_amdgcn_mfma_f32_16x16x32_bf16(a[mi], b, acc[mi][ni], 0, 0, 0);
        }
        __syncthreads();
    }

    #pragma unroll
    for (int mi = 0; mi < 2; mi++) {
        int r0 = wr * 32 + mi * 16 + l4 * 4;
        #pragma unroll
        for (int ni = 0; ni < 8; ni++) {
            int gc = wc * 128 + ni * 16 + l15;
            float bv = bmlp[gc];
            int cc = gc >> 3, c7 = gc & 7;
            #pragma unroll
            for (int q = 0; q < 4; q++) {
                int row = r0 + q;
                float v = fmaxf(acc[mi][ni][q] + bv, 0.f);
                h0s[row * 256 + ((cc ^ (row & 7)) << 3) + c7] = (short)f2bf(v);
            }
        }
    }

    #pragma unroll
    for (int i = 0; i < 2; i++)
        #pragma unroll
        for (int j = 0; j < 8; j++) acc[i][j] = (f32x4){0.f, 0.f, 0.f, 0.f};

    for (int k2 = 0; k2 < NH; k2 += 32) {
        #pragma unroll
        for (int i = 0; i < 2; i++) {
            int ch = tid + i * 512;
            int row = ch >> 2, c = ch & 3;
            int sw = c ^ (row & 3) ^ ((row >> 2) & 3);
            bf16x8 w = *(const bf16x8*)(W1T + (long)row * NH + k2 + c * 8);
            *(bf16x8*)(Bs2 + row * 32 + sw * 8) = w;
        }
        __syncthreads();

        bf16x8 a[2];
        #pragma unroll
        for (int mi = 0; mi < 2; mi++) {
            int row = wr * 32 + mi * 16 + l15;
            int cc = (k2 >> 3) + g;
            a[mi] = *(const bf16x8*)(h0s + row * 256 + ((cc ^ (row & 7)) << 3));
        }
        #pragma unroll
        for (int ni = 0; ni < 8; ni++) {
            int row = wc * 128 + ni * 16 + l15;
            int sw = g ^ (row & 3) ^ ((row >> 2) & 3);
            bf16x8 b = *(const bf16x8*)(Bs2 + row * 32 + sw * 8);
            #pragma unroll
            for (int mi = 0; mi < 2; mi++)
                acc[mi][ni] = __builtin_amdgcn_mfma_f32_16x16x32_bf16(a[mi], b, acc[mi][ni], 0, 0, 0);
        }
        __syncthreads();
    }

    #pragma unroll
    for (int mi = 0; mi < 2; mi++) {
        long gr0 = bm + wr * 32 + mi * 16 + l4 * 4;
        #pragma unroll
        for (int ni = 0; ni < 8; ni++) {
            int gc = wc * 128 + ni * 16 + l15;
            #pragma unroll
            for (int q = 0; q < 4; q++) {
                long gr = gr0 + q;
                if (gr < M) t1[gr * NH + gc] = f2bf(acc[mi][ni][q]);
            }
        }
    }
}

// ---------------- GEMM3 (h1 @ W2 -> split planes t2A[NN][32], t2B[NN][8]) ----------------
__global__ __launch_bounds__(256)
void gemm3_kernel(const unsigned short* __restrict__ A, const unsigned short* __restrict__ W2T,
                  unsigned short* __restrict__ t2A, unsigned short* __restrict__ t2B, int M) {
    constexpr int BM = 128, BK = 32;
    __shared__ short As[BM * BK];
    __shared__ short Bs[64 * BK];

    const int tid = threadIdx.x;
    const int lane = tid & 63;
    const int wid = tid >> 6;
    const int wr = wid;
    const long bm = (long)blockIdx.x * BM;
    const int l15 = lane & 15, g = lane >> 4, l4 = lane >> 4;

    f32x4 acc[2][4];
    #pragma unroll
    for (int i = 0; i < 2; i++)
        #pragma unroll
        for (int j = 0; j < 4; j++) acc[i][j] = (f32x4){0.f, 0.f, 0.f, 0.f};

    for (int k0 = 0; k0 < NH; k0 += BK) {
        #pragma unroll
        for (int i = 0; i < 2; i++) {
            int ch = tid + i * 256;
            int row = ch >> 2, c = ch & 3;
            int sw = c ^ (row & 3) ^ ((row >> 2) & 3);
            long gr = bm + row;
            bf16x8 w = (bf16x8){0, 0, 0, 0, 0, 0, 0, 0};
            if (gr < M) w = *(const bf16x8*)(A + gr * NH + k0 + c * 8);
            *(bf16x8*)(&As[row * BK + sw * 8]) = w;
        }
        {
            int ch = tid;
            int row = ch >> 2, c = ch & 3;
            int sw = c ^ (row & 3) ^ ((row >> 2) & 3);
            bf16x8 w = *(const bf16x8*)(W2T + (long)row * NH + k0 + c * 8);
            *(bf16x8*)(&Bs[row * BK + sw * 8]) = w;
        }
        __syncthreads();

        bf16x8 a[2];
        #pragma unroll
        for (int mi = 0; mi < 2; mi++) {
            int row = wr * 32 + mi * 16 + l15;
            int sw = g ^ (row & 3) ^ ((row >> 2) & 3);
            a[mi] = *(const bf16x8*)(&As[row * BK + sw * 8]);
        }
        #pragma unroll
        for (int ni = 0; ni < 4; ni++) {
            int row = ni * 16 + l15;
            int sw = g ^ (row & 3) ^ ((row >> 2) & 3);
            bf16x8 b = *(const bf16x8*)(&Bs[row * BK + sw * 8]);
            #pragma unroll
            for (int mi = 0; mi < 2; mi++)
                acc[mi][ni] = __builtin_amdgcn_mfma_f32_16x16x32_bf16(a[mi], b, acc[mi][ni], 0, 0, 0);
        }
        __syncthreads();
    }

    #pragma unroll
    for (int mi = 0; mi < 2; mi++) {
        long gr0 = bm + wr * 32 + mi * 16 + l4 * 4;
        #pragma unroll
        for (int ni = 0; ni < 4; ni++) {
            int gc = ni * 16 + l15;
            if (gc >= NC) continue;
            #pragma unroll
            for (int q = 0; q < 4; q++) {
                long gr = gr0 + q;
                if (gr >= M) continue;
                unsigned short v = f2bf(acc[mi][ni][q]);
                if (gc < 32) t2A[gr * 32 + gc] = v;
                else         t2B[gr * 8 + (gc - 32)] = v;
            }
        }
    }
}

// ---------------- aggregation (gather SpMM, bf16 payload, int2 edge records) ----------------
__global__ void agg256_kernel(const unsigned short* __restrict__ t, const int* __restrict__ row_ptr,
                              const int2* __restrict__ csr, const float* __restrict__ dis,
                              const float* __restrict__ bias, unsigned short* __restrict__ out, int n) {
    const int wid = threadIdx.x >> 6, lane = threadIdx.x & 63;
    const int node = blockIdx.x * 4 + wid;
    if (node >= n) return;
    const int half = lane >> 5;
    const int f0 = (lane & 31) * 8;
    const float d = dis[node];
    float a[8];
    if (half == 0) {
        u16x8 sv = *(const u16x8*)(t + (long)node * NH + f0);
        float d2 = d * d;
        #pragma unroll
        for (int j = 0; j < 8; j++) a[j] = bf2f(sv[j]) * d2;
    } else {
        #pragma unroll
        for (int j = 0; j < 8; j++) a[j] = 0.f;
    }
    const int lo = row_ptr[node], hi = row_ptr[node + 1];
    int ee = lo + half;
    for (; ee + 6 < hi; ee += 8) {
        int2 r0 = csr[ee];
        int2 r1 = csr[ee + 2];
        int2 r2 = csr[ee + 4];
        int2 r3 = csr[ee + 6];
        u16x8 v0 = *(const u16x8*)(t + (long)r0.x * NH + f0);
        u16x8 v1 = *(const u16x8*)(t + (long)r1.x * NH + f0);
        u16x8 v2 = *(const u16x8*)(t + (long)r2.x * NH + f0);
        u16x8 v3 = *(const u16x8*)(t + (long)r3.x * NH + f0);
        float w0 = __int_as_float(r0.y), w1 = __int_as_float(r1.y);
        float w2 = __int_as_float(r2.y), w3 = __int_as_float(r3.y);
        #pragma unroll
        for (int j = 0; j < 8; j++)
            a[j] += (bf2f(v0[j]) * w0 + bf2f(v1[j]) * w1) + (bf2f(v2[j]) * w2 + bf2f(v3[j]) * w3);
    }
    for (; ee + 2 < hi; ee += 4) {
        int2 r0 = csr[ee];
        int2 r1 = csr[ee + 2];
        u16x8 v0 = *(const u16x8*)(t + (long)r0.x * NH + f0);
        u16x8 v1 = *(const u16x8*)(t + (long)r1.x * NH + f0);
        float w0 = __int_as_float(r0.y), w1 = __int_as_float(r1.y);
        #pragma unroll
        for (int j = 0; j < 8; j++)
            a[j] += bf2f(v0[j]) * w0 + bf2f(v1[j]) * w1;
    }
    if (ee < hi) {
        int2 r0 = csr[ee];
        u16x8 v0 = *(const u16x8*)(t + (long)r0.x * NH + f0);
        float w0 = __int_as_float(r0.y);
        #pragma unroll
        for (int j = 0; j < 8; j++) a[j] += bf2f(v0[j]) * w0;
    }
    #pragma unroll
    for (int j = 0; j < 8; j++) a[j] += __shfl_xor(a[j], 32);
    if (half == 0) {
        u16x8 o;
        #pragma unroll
        for (int j = 0; j < 8; j++)
            o[j] = f2bf(fmaxf(a[j] + bias[f0 + j], 0.f));
        *(u16x8*)(out + (long)node * NH + f0) = o;
    }
}

// agg40: split planes t2A[NN][32] (64B rows) + t2B[NN][8] (L2-resident).
__global__ void agg40_kernel(const unsigned short* __restrict__ tA, const unsigned short* __restrict__ tB,
                             const int* __restrict__ row_ptr, const int2* __restrict__ csr,
                             const float* __restrict__ dis, const float* __restrict__ bias,
                             float* __restrict__ out, int n) {
    const int wid = threadIdx.x >> 6, lane = threadIdx.x & 63;
    const int node = blockIdx.x * 4 + wid;
    if (node >= n) return;
    const int g = lane >> 3;
    const int s = lane & 7;
    const int f0 = s * 8;
    const bool act = f0 < NC;
    const unsigned short* gp = (s < 4) ? tA : tB;
    const int ss = (s < 4) ? 5 : 3;
    const int fo = (s < 4) ? f0 : 0;
    const float d = dis[node];
    float a[8];
    #pragma unroll
    for (int j = 0; j < 8; j++) a[j] = 0.f;
    const int lo = row_ptr[node], hi = row_ptr[node + 1];
    if (act) {
        if (g == 0) {
            u16x8 sv = *(const u16x8*)(gp + (((size_t)node) << ss) + fo);
            float d2 = d * d;
            #pragma unroll
            for (int j = 0; j < 8; j++) a[j] = bf2f(sv[j]) * d2;
        }
        int ee = lo + g;
        for (; ee + 8 < hi; ee += 16) {
            int2 r0 = csr[ee];
            int2 r1 = csr[ee + 8];
            u16x8 v0 = *(const u16x8*)(gp + (((size_t)r0.x) << ss) + fo);
            u16x8 v1 = *(const u16x8*)(gp + (((size_t)r1.x) << ss) + fo);
            float w0 = __int_as_float(r0.y), w1 = __int_as_float(r1.y);
            #pragma unroll
            for (int j = 0; j < 8; j++)
                a[j] += bf2f(v0[j]) * w0 + bf2f(v1[j]) * w1;
        }
        if (ee < hi) {
            int2 r0 = csr[ee];
            u16x8 v0 = *(const u16x8*)(gp + (((size_t)r0.x) << ss) + fo);
            float w0 = __int_as_float(r0.y);
            #pragma unroll
            for (int j = 0; j < 8; j++) a[j] += bf2f(v0[j]) * w0;
        }
    }
    #pragma unroll
    for (int st = 8; st < 64; st <<= 1)
        #pragma unroll
        for (int j = 0; j < 8; j++) a[j] += __shfl_xor(a[j], st);
    if (g == 0 && act) {
        float4 o0, o1;
        o0.x = a[0] + bias[f0 + 0]; o0.y = a[1] + bias[f0 + 1];
        o0.z = a[2] + bias[f0 + 2]; o0.w = a[3] + bias[f0 + 3];
        o1.x = a[4] + bias[f0 + 4]; o1.y = a[5] + bias[f0 + 5];
        o1.z = a[6] + bias[f0 + 6]; o1.w = a[7] + bias[f0 + 7];
        float* dst = out + (long)node * NC + f0;
        *(float4*)dst = o0;
        *(float4*)(dst + 4) = o1;
    }
}

// ---------------- launch ----------------

extern "C" void kernel_launch(void* const* d_in, const int* in_sizes, int n_in,
                              void* d_out, int out_size, void* d_ws, size_t ws_size,
                              hipStream_t stream) {
    const float* x     = (const float*)d_in[0];
    const int*   ei    = (const int*)d_in[1];
    const float* W_mlp = (const float*)d_in[2];
    const float* b_mlp = (const float*)d_in[3];
    const float* W1    = (const float*)d_in[4];
    const float* b1    = (const float*)d_in[5];
    const float* W2    = (const float*)d_in[6];
    const float* b2    = (const float*)d_in[7];
    float* out = (float*)d_out;

    // workspace layout (float units)
    float* ws = (float*)d_ws;
    size_t off = 0;
    float*    dis     = ws + off; off += 100096;
    int*      row_cnt = (int*)(ws + off); off += 100096;
    int*      row_ptr = (int*)(ws + off); off += 100096;
    int*      bsum    = (int*)(ws + off); off += 512;
    int*      boff    = (int*)(ws + off); off += 512;
    unsigned char* rpart8 = (unsigned char*)(ws + off); off += (size_t)PARTS * NPAD / 4;
    unsigned char* cpart8 = (unsigned char*)(ws + off); off += (size_t)PARTS * NPAD / 4;
    unsigned char* rbase8 = (unsigned char*)(ws + off); off += (size_t)PARTS * NPAD / 4;
    int2*     csr     = (int2*)(ws + off); off += (size_t)NE * 2;
    unsigned short* WTm = (unsigned short*)(ws + off); off += (NH * NF) / 2;
    unsigned short* W1T = (unsigned short*)(ws + off); off += (NH * NH) / 2;
    unsigned short* W2T = (unsigned short*)(ws + off); off += (64 * NH) / 2;
    unsigned short* t1  = (unsigned short*)(ws + off); off += (size_t)NN * NH / 2;
    unsigned short* h1  = (unsigned short*)(ws + off); off += (size_t)NN * NH / 2;
    unsigned short* t2A = (unsigned short*)(ws + off); off += (size_t)NN * 32 / 2;
    unsigned short* t2B = (unsigned short*)(ws + off); off += (size_t)NN * 8 / 2;
    (void)ws_size;

    dim3 gh(NCH2, PARTS, 2);
    hist2_kernel<<<gh, 512, 0, stream>>>(ei, rpart8, cpart8);
    reduce_kernel<<<NBLK, 256, 0, stream>>>(rpart8, cpart8, row_cnt, dis, bsum);
    scanb_kernel<<<1, 512, 0, stream>>>(bsum, boff);
    rstart2_kernel<<<NBLK, 256, 0, stream>>>(rpart8, row_cnt, boff, row_ptr, rbase8);
    dim3 gf(NCH, PARTS);
    fill2d_kernel<<<gf, 512, 0, stream>>>(ei, rbase8, row_ptr, dis, csr);

    wtrans_all<<<(NH * NF + NH * NH + 64 * NH + 255) / 256, 256, 0, stream>>>(
        W_mlp, W1, W2, WTm, W1T, W2T);

    const int mb = (NN + 127) / 128;  // 782
    // t1 = (relu(x@Wm+b)) @ W1, fused (h0 stays in LDS)
    gemm12_kernel<<<mb, 512, 0, stream>>>(x, WTm, b_mlp, W1T, t1, NN);
    // h1 = relu(agg(t1) + b1)
    agg256_kernel<<<(NN + 3) / 4, 256, 0, stream>>>(t1, row_ptr, csr, dis, b1, h1, NN);
    // t2A/t2B = h1 @ W2 (split 32+8 planes)
    gemm3_kernel<<<mb, 256, 0, stream>>>(h1, W2T, t2A, t2B, NN);
    // out = agg(t2A,t2B) + b2
    agg40_kernel<<<(NN + 3) / 4, 256, 0, stream>>>(t2A, t2B, row_ptr, csr, dis, b2, out, NN);
}

// Round 13
// 571.038 us; speedup vs baseline: 1.5633x; 1.0061x over previous
//
#include <hip/hip_runtime.h>

// GCNPre: N=100000 nodes, E=3200000 edges, F=512, H=256, C=40.
#define NN 100000
#define NE 3200000
#define NF 512
#define NH 256
#define NC 40

// CSR-build partitioning.
#define CH 32768                     // fill chunk (u16 cursors, 64KB LDS, 256 blocks)
#define NCH 4
#define CH2 65536                    // hist chunk (u8 counters, 64KB LDS, 256 blocks)
#define NCH2 2
#define NPAD (NCH * CH)              // 131072
#define PARTS 64
#define SLICE ((NE + PARTS - 1) / PARTS)   // 50000
#define NBLK ((NN + 255) / 256)      // 391
#define WT_ELEMS (NH * NF + NH * NH + 64 * NH)   // 212992 = 416*512

typedef __attribute__((ext_vector_type(8))) short bf16x8;
typedef __attribute__((ext_vector_type(4))) float f32x4;
typedef __attribute__((ext_vector_type(4))) unsigned short u16x4;
typedef __attribute__((ext_vector_type(8))) unsigned short u16x8;

__device__ inline unsigned short f2bf(float f) {
    union { float f; unsigned u; } v; v.f = f;
    unsigned r = v.u + 0x7fffu + ((v.u >> 16) & 1u);
    return (unsigned short)(r >> 16);
}
__device__ inline float bf2f(unsigned short s) {
    union { unsigned u; float f; } v; v.u = ((unsigned)s) << 16;
    return v.f;
}

// ---------------- fused histogram + weight transpose ----------------
// Blocks 0..255: u8-packed 64KB LDS histogram (chunk2, part, which).
// Blocks 256..671: weight transpose + bf16 cast (independent work, hidden here).
__global__ __launch_bounds__(512) void histw_kernel(const int* __restrict__ ei,
                                                    unsigned char* __restrict__ rpart8,
                                                    unsigned char* __restrict__ cpart8,
                                                    const float* __restrict__ Wm,
                                                    const float* __restrict__ W1,
                                                    const float* __restrict__ W2,
                                                    unsigned short* __restrict__ WTm,
                                                    unsigned short* __restrict__ W1T,
                                                    unsigned short* __restrict__ W2T) {
    __shared__ unsigned h[CH2 / 4];   // 64KB
    const int bid = blockIdx.x;
    if (bid < 2 * PARTS * 2) {
        const int chunk = bid & 1, part = (bid >> 1) & 63, which = bid >> 7;
        const int* src = which ? (ei + NE) : ei;
        unsigned char* outp = which ? cpart8 : rpart8;
        const int lo = chunk * CH2;
        for (int i = threadIdx.x; i < CH2 / 4; i += 512) h[i] = 0;
        __syncthreads();
        const int e1 = min((part + 1) * SLICE, NE);
        for (int e = part * SLICE + threadIdx.x; e < e1; e += 512) {
            unsigned v = (unsigned)(src[e] - lo);
            if (v < CH2) atomicAdd(&h[v >> 2], 1u << ((v & 3) << 3));
        }
        __syncthreads();
        unsigned* dst = (unsigned*)(outp + (size_t)part * NPAD + lo);
        for (int i = threadIdx.x; i < CH2 / 4; i += 512) dst[i] = h[i];
    } else {
        int t = (bid - 2 * PARTS * 2) * 512 + threadIdx.x;
        if (t < NH * NF) {                   // WTm[n][k] = Wm[k][n]
            int n = t / NF, k = t % NF;
            WTm[t] = f2bf(Wm[(long)k * NH + n]);
            return;
        }
        t -= NH * NF;
        if (t < NH * NH) {                   // W1T[n][k] = W1[k][n]
            int n = t / NH, k = t % NH;
            W1T[t] = f2bf(W1[(long)k * NH + n]);
            return;
        }
        t -= NH * NH;
        if (t < 64 * NH) {                   // W2T[n][k] = W2[k][n], padded to 64 rows
            int n = t / NH, k = t % NH;
            W2T[t] = (n < NC) ? f2bf(W2[(long)k * NC + n]) : (unsigned short)0;
        }
    }
}

__global__ __launch_bounds__(256) void reduce_kernel(const unsigned char* __restrict__ rpart8,
                                                     const unsigned char* __restrict__ cpart8,
                                                     int* __restrict__ row_cnt, float* __restrict__ dis,
                                                     int* __restrict__ bsum) {
    __shared__ int s[256];
    const int tid = threadIdx.x;
    const int v = blockIdx.x * 256 + tid;
    unsigned rs = 0, cs = 0;
    if (v < NN) {
        #pragma unroll 1
        for (int p = 0; p < PARTS; p++) {
            rs += rpart8[(size_t)p * NPAD + v];
            cs += cpart8[(size_t)p * NPAD + v];
        }
        row_cnt[v] = (int)rs;
        dis[v] = rsqrtf((float)cs + 1.0f);
    }
    s[tid] = (int)rs;
    __syncthreads();
    #pragma unroll
    for (int o = 128; o > 0; o >>= 1) {
        if (tid < o) s[tid] += s[tid + o];
        __syncthreads();
    }
    if (tid == 0) bsum[blockIdx.x] = s[0];
}

// row_ptr[v] = boff(bid) + intra-block scan; rbase8[p][v] = within-row prefix (u8).
// boff computed per-block as a parallel reduce over bsum[0..bid-1] (391 ints, L2-hot).
__global__ __launch_bounds__(256) void rstart2_kernel(const unsigned char* __restrict__ rpart8,
                                                      const int* __restrict__ row_cnt,
                                                      const int* __restrict__ bsum,
                                                      int* __restrict__ row_ptr,
                                                      unsigned char* __restrict__ rbase8) {
    __shared__ int s[256];
    __shared__ int btot;
    const int tid = threadIdx.x;
    const int bid = blockIdx.x;
    int ps = 0;
    for (int i = tid; i < bid; i += 256) ps += bsum[i];
    s[tid] = ps;
    __syncthreads();
    #pragma unroll
    for (int o = 128; o > 0; o >>= 1) {
        if (tid < o) s[tid] += s[tid + o];
        __syncthreads();
    }
    if (tid == 0) btot = s[0];
    __syncthreads();
    const int boff = btot;

    const int v = bid * 256 + tid;
    int cnt = (v < NN) ? row_cnt[v] : 0;
    __syncthreads();
    s[tid] = cnt;
    __syncthreads();
    #pragma unroll
    for (int o = 1; o < 256; o <<= 1) {
        int u = (tid >= o) ? s[tid - o] : 0;
        __syncthreads();
        s[tid] += u;
        __syncthreads();
    }
    if (v < NN) {
        row_ptr[v] = boff + s[tid] - cnt;
        unsigned off = 0;
        #pragma unroll 1
        for (int p = 0; p < PARTS; p++) {
            size_t i = (size_t)p * NPAD + v;
            rbase8[i] = (unsigned char)off;
            off += rpart8[i];
        }
    }
    if (v == NN) row_ptr[NN] = NE;
}

// Fill packed CSR records {col, w}: idx = row_ptr[r] + rbase8[part][r] + LDS cursor.
__global__ __launch_bounds__(512) void fill2d_kernel(const int* __restrict__ ei,
                                                     const unsigned char* __restrict__ rbase8,
                                                     const int* __restrict__ row_ptr,
                                                     const float* __restrict__ dis,
                                                     int2* __restrict__ csr) {
    __shared__ unsigned cur[CH / 2];
    const int chunk = blockIdx.x, part = blockIdx.y;
    const int lo = chunk * CH;
    for (int i = threadIdx.x; i < CH / 2; i += 512) cur[i] = 0;
    __syncthreads();
    const unsigned char* base8 = rbase8 + (size_t)part * NPAD;
    const int e1 = min((part + 1) * SLICE, NE);
    for (int e = part * SLICE + threadIdx.x; e < e1; e += 512) {
        int r = ei[e];
        unsigned rr = (unsigned)(r - lo);
        if (rr < CH) {
            int c = ei[NE + e];
            unsigned sh = (rr & 1) << 4;
            unsigned old = atomicAdd(&cur[rr >> 1], 1u << sh);
            unsigned p = (old >> sh) & 0xffffu;
            unsigned idx = (unsigned)row_ptr[r] + base8[r] + p;
            int2 rec;
            rec.x = c;
            rec.y = __float_as_int(dis[r] * dis[c]);
            csr[idx] = rec;
        }
    }
}

// ---------------- fused GEMM1+GEMM2 ----------------
__global__ __launch_bounds__(512)
void gemm12_kernel(const float* __restrict__ x, const unsigned short* __restrict__ WTm,
                   const float* __restrict__ bmlp, const unsigned short* __restrict__ W1T,
                   unsigned short* __restrict__ t1, int M) {
    __shared__ char smem[81920];
    short* h0s = (short*)smem;                 // [128][256] bf16, chunk-swizzled (64KB)
    short* As  = (short*)smem;                 // stage1 A [128][32]
    short* Bs  = (short*)(smem + 8192);        // stage1 B [256][32]
    short* Bs2 = (short*)(smem + 65536);       // stage2 B [256][32]

    const int tid = threadIdx.x;
    const int lane = tid & 63;
    const int wid = tid >> 6;
    const int wr = wid >> 1;
    const int wc = wid & 1;
    const long bm = (long)blockIdx.x * 128;
    const int l15 = lane & 15, g = lane >> 4, l4 = lane >> 4;

    f32x4 acc[2][8];
    #pragma unroll
    for (int i = 0; i < 2; i++)
        #pragma unroll
        for (int j = 0; j < 8; j++) acc[i][j] = (f32x4){0.f, 0.f, 0.f, 0.f};

    for (int k0 = 0; k0 < NF; k0 += 32) {
        {
            int ch = tid;
            int row = ch >> 2, c = ch & 3;
            int sw = c ^ (row & 3) ^ ((row >> 2) & 3);
            long gr = bm + row;
            bf16x8 w = (bf16x8){0, 0, 0, 0, 0, 0, 0, 0};
            if (gr < M) {
                float4 v0 = *(const float4*)(x + gr * NF + k0 + c * 8);
                float4 v1 = *(const float4*)(x + gr * NF + k0 + c * 8 + 4);
                w[0] = (short)f2bf(v0.x); w[1] = (short)f2bf(v0.y);
                w[2] = (short)f2bf(v0.z); w[3] = (short)f2bf(v0.w);
                w[4] = (short)f2bf(v1.x); w[5] = (short)f2bf(v1.y);
                w[6] = (short)f2bf(v1.z); w[7] = (short)f2bf(v1.w);
            }
            *(bf16x8*)(As + row * 32 + sw * 8) = w;
        }
        #pragma unroll
        for (int i = 0; i < 2; i++) {
            int ch = tid + i * 512;
            int row = ch >> 2, c = ch & 3;
            int sw = c ^ (row & 3) ^ ((row >> 2) & 3);
            bf16x8 w = *(const bf16x8*)(WTm + (long)row * NF + k0 + c * 8);
            *(bf16x8*)(Bs + row * 32 + sw * 8) = w;
        }
        __syncthreads();

        bf16x8 a[2];
        #pragma unroll
        for (int mi = 0; mi < 2; mi++) {
            int row = wr * 32 + mi * 16 + l15;
            int sw = g ^ (row & 3) ^ ((row >> 2) & 3);
            a[mi] = *(const bf16x8*)(As + row * 32 + sw * 8);
        }
        #pragma unroll
        for (int ni = 0; ni < 8; ni++) {
            int row = wc * 128 + ni * 16 + l15;
            int sw = g ^ (row & 3) ^ ((row >> 2) & 3);
            bf16x8 b = *(const bf16x8*)(Bs + row * 32 + sw * 8);
            #pragma unroll
            for (int mi = 0; mi < 2; mi++)
                acc[mi][ni] = __builtin_amdgcn_mfma_f32_16x16x32_bf16(a[mi], b, acc[mi][ni], 0, 0, 0);
        }
        __syncthreads();
    }

    #pragma unroll
    for (int mi = 0; mi < 2; mi++) {
        int r0 = wr * 32 + mi * 16 + l4 * 4;
        #pragma unroll
        for (int ni = 0; ni < 8; ni++) {
            int gc = wc * 128 + ni * 16 + l15;
            float bv = bmlp[gc];
            int cc = gc >> 3, c7 = gc & 7;
            #pragma unroll
            for (int q = 0; q < 4; q++) {
                int row = r0 + q;
                float v = fmaxf(acc[mi][ni][q] + bv, 0.f);
                h0s[row * 256 + ((cc ^ (row & 7)) << 3) + c7] = (short)f2bf(v);
            }
        }
    }

    #pragma unroll
    for (int i = 0; i < 2; i++)
        #pragma unroll
        for (int j = 0; j < 8; j++) acc[i][j] = (f32x4){0.f, 0.f, 0.f, 0.f};

    for (int k2 = 0; k2 < NH; k2 += 32) {
        #pragma unroll
        for (int i = 0; i < 2; i++) {
            int ch = tid + i * 512;
            int row = ch >> 2, c = ch & 3;
            int sw = c ^ (row & 3) ^ ((row >> 2) & 3);
            bf16x8 w = *(const bf16x8*)(W1T + (long)row * NH + k2 + c * 8);
            *(bf16x8*)(Bs2 + row * 32 + sw * 8) = w;
        }
        __syncthreads();

        bf16x8 a[2];
        #pragma unroll
        for (int mi = 0; mi < 2; mi++) {
            int row = wr * 32 + mi * 16 + l15;
            int cc = (k2 >> 3) + g;
            a[mi] = *(const bf16x8*)(h0s + row * 256 + ((cc ^ (row & 7)) << 3));
        }
        #pragma unroll
        for (int ni = 0; ni < 8; ni++) {
            int row = wc * 128 + ni * 16 + l15;
            int sw = g ^ (row & 3) ^ ((row >> 2) & 3);
            bf16x8 b = *(const bf16x8*)(Bs2 + row * 32 + sw * 8);
            #pragma unroll
            for (int mi = 0; mi < 2; mi++)
                acc[mi][ni] = __builtin_amdgcn_mfma_f32_16x16x32_bf16(a[mi], b, acc[mi][ni], 0, 0, 0);
        }
        __syncthreads();
    }

    #pragma unroll
    for (int mi = 0; mi < 2; mi++) {
        long gr0 = bm + wr * 32 + mi * 16 + l4 * 4;
        #pragma unroll
        for (int ni = 0; ni < 8; ni++) {
            int gc = wc * 128 + ni * 16 + l15;
            #pragma unroll
            for (int q = 0; q < 4; q++) {
                long gr = gr0 + q;
                if (gr < M) t1[gr * NH + gc] = f2bf(acc[mi][ni][q]);
            }
        }
    }
}

// ---------------- GEMM3 (h1 @ W2 -> split planes t2A[NN][32], t2B[NN][8]) ----------------
__global__ __launch_bounds__(256)
void gemm3_kernel(const unsigned short* __restrict__ A, const unsigned short* __restrict__ W2T,
                  unsigned short* __restrict__ t2A, unsigned short* __restrict__ t2B, int M) {
    constexpr int BM = 128, BK = 32;
    __shared__ short As[BM * BK];
    __shared__ short Bs[64 * BK];

    const int tid = threadIdx.x;
    const int lane = tid & 63;
    const int wid = tid >> 6;
    const int wr = wid;
    const long bm = (long)blockIdx.x * BM;
    const int l15 = lane & 15, g = lane >> 4, l4 = lane >> 4;

    f32x4 acc[2][4];
    #pragma unroll
    for (int i = 0; i < 2; i++)
        #pragma unroll
        for (int j = 0; j < 4; j++) acc[i][j] = (f32x4){0.f, 0.f, 0.f, 0.f};

    for (int k0 = 0; k0 < NH; k0 += BK) {
        #pragma unroll
        for (int i = 0; i < 2; i++) {
            int ch = tid + i * 256;
            int row = ch >> 2, c = ch & 3;
            int sw = c ^ (row & 3) ^ ((row >> 2) & 3);
            long gr = bm + row;
            bf16x8 w = (bf16x8){0, 0, 0, 0, 0, 0, 0, 0};
            if (gr < M) w = *(const bf16x8*)(A + gr * NH + k0 + c * 8);
            *(bf16x8*)(&As[row * BK + sw * 8]) = w;
        }
        {
            int ch = tid;
            int row = ch >> 2, c = ch & 3;
            int sw = c ^ (row & 3) ^ ((row >> 2) & 3);
            bf16x8 w = *(const bf16x8*)(W2T + (long)row * NH + k0 + c * 8);
            *(bf16x8*)(&Bs[row * BK + sw * 8]) = w;
        }
        __syncthreads();

        bf16x8 a[2];
        #pragma unroll
        for (int mi = 0; mi < 2; mi++) {
            int row = wr * 32 + mi * 16 + l15;
            int sw = g ^ (row & 3) ^ ((row >> 2) & 3);
            a[mi] = *(const bf16x8*)(&As[row * BK + sw * 8]);
        }
        #pragma unroll
        for (int ni = 0; ni < 4; ni++) {
            int row = ni * 16 + l15;
            int sw = g ^ (row & 3) ^ ((row >> 2) & 3);
            bf16x8 b = *(const bf16x8*)(&Bs[row * BK + sw * 8]);
            #pragma unroll
            for (int mi = 0; mi < 2; mi++)
                acc[mi][ni] = __builtin_amdgcn_mfma_f32_16x16x32_bf16(a[mi], b, acc[mi][ni], 0, 0, 0);
        }
        __syncthreads();
    }

    #pragma unroll
    for (int mi = 0; mi < 2; mi++) {
        long gr0 = bm + wr * 32 + mi * 16 + l4 * 4;
        #pragma unroll
        for (int ni = 0; ni < 4; ni++) {
            int gc = ni * 16 + l15;
            if (gc >= NC) continue;
            #pragma unroll
            for (int q = 0; q < 4; q++) {
                long gr = gr0 + q;
                if (gr >= M) continue;
                unsigned short v = f2bf(acc[mi][ni][q]);
                if (gc < 32) t2A[gr * 32 + gc] = v;
                else         t2B[gr * 8 + (gc - 32)] = v;
            }
        }
    }
}

// ---------------- aggregation (gather SpMM, bf16 payload, int2 edge records) ----------------
__global__ void agg256_kernel(const unsigned short* __restrict__ t, const int* __restrict__ row_ptr,
                              const int2* __restrict__ csr, const float* __restrict__ dis,
                              const float* __restrict__ bias, unsigned short* __restrict__ out, int n) {
    const int wid = threadIdx.x >> 6, lane = threadIdx.x & 63;
    const int node = blockIdx.x * 4 + wid;
    if (node >= n) return;
    const int half = lane >> 5;
    const int f0 = (lane & 31) * 8;
    const float d = dis[node];
    float a[8];
    if (half == 0) {
        u16x8 sv = *(const u16x8*)(t + (long)node * NH + f0);
        float d2 = d * d;
        #pragma unroll
        for (int j = 0; j < 8; j++) a[j] = bf2f(sv[j]) * d2;
    } else {
        #pragma unroll
        for (int j = 0; j < 8; j++) a[j] = 0.f;
    }
    const int lo = row_ptr[node], hi = row_ptr[node + 1];
    int ee = lo + half;
    for (; ee + 6 < hi; ee += 8) {
        int2 r0 = csr[ee];
        int2 r1 = csr[ee + 2];
        int2 r2 = csr[ee + 4];
        int2 r3 = csr[ee + 6];
        u16x8 v0 = *(const u16x8*)(t + (long)r0.x * NH + f0);
        u16x8 v1 = *(const u16x8*)(t + (long)r1.x * NH + f0);
        u16x8 v2 = *(const u16x8*)(t + (long)r2.x * NH + f0);
        u16x8 v3 = *(const u16x8*)(t + (long)r3.x * NH + f0);
        float w0 = __int_as_float(r0.y), w1 = __int_as_float(r1.y);
        float w2 = __int_as_float(r2.y), w3 = __int_as_float(r3.y);
        #pragma unroll
        for (int j = 0; j < 8; j++)
            a[j] += (bf2f(v0[j]) * w0 + bf2f(v1[j]) * w1) + (bf2f(v2[j]) * w2 + bf2f(v3[j]) * w3);
    }
    for (; ee + 2 < hi; ee += 4) {
        int2 r0 = csr[ee];
        int2 r1 = csr[ee + 2];
        u16x8 v0 = *(const u16x8*)(t + (long)r0.x * NH + f0);
        u16x8 v1 = *(const u16x8*)(t + (long)r1.x * NH + f0);
        float w0 = __int_as_float(r0.y), w1 = __int_as_float(r1.y);
        #pragma unroll
        for (int j = 0; j < 8; j++)
            a[j] += bf2f(v0[j]) * w0 + bf2f(v1[j]) * w1;
    }
    if (ee < hi) {
        int2 r0 = csr[ee];
        u16x8 v0 = *(const u16x8*)(t + (long)r0.x * NH + f0);
        float w0 = __int_as_float(r0.y);
        #pragma unroll
        for (int j = 0; j < 8; j++) a[j] += bf2f(v0[j]) * w0;
    }
    #pragma unroll
    for (int j = 0; j < 8; j++) a[j] += __shfl_xor(a[j], 32);
    if (half == 0) {
        u16x8 o;
        #pragma unroll
        for (int j = 0; j < 8; j++)
            o[j] = f2bf(fmaxf(a[j] + bias[f0 + j], 0.f));
        *(u16x8*)(out + (long)node * NH + f0) = o;
    }
}

// agg40: split planes t2A[NN][32] (64B rows) + t2B[NN][8] (L2-resident).
__global__ void agg40_kernel(const unsigned short* __restrict__ tA, const unsigned short* __restrict__ tB,
                             const int* __restrict__ row_ptr, const int2* __restrict__ csr,
                             const float* __restrict__ dis, const float* __restrict__ bias,
                             float* __restrict__ out, int n) {
    const int wid = threadIdx.x >> 6, lane = threadIdx.x & 63;
    const int node = blockIdx.x * 4 + wid;
    if (node >= n) return;
    const int g = lane >> 3;
    const int s = lane & 7;
    const int f0 = s * 8;
    const bool act = f0 < NC;
    const unsigned short* gp = (s < 4) ? tA : tB;
    const int ss = (s < 4) ? 5 : 3;
    const int fo = (s < 4) ? f0 : 0;
    const float d = dis[node];
    float a[8];
    #pragma unroll
    for (int j = 0; j < 8; j++) a[j] = 0.f;
    const int lo = row_ptr[node], hi = row_ptr[node + 1];
    if (act) {
        if (g == 0) {
            u16x8 sv = *(const u16x8*)(gp + (((size_t)node) << ss) + fo);
            float d2 = d * d;
            #pragma unroll
            for (int j = 0; j < 8; j++) a[j] = bf2f(sv[j]) * d2;
        }
        int ee = lo + g;
        for (; ee + 8 < hi; ee += 16) {
            int2 r0 = csr[ee];
            int2 r1 = csr[ee + 8];
            u16x8 v0 = *(const u16x8*)(gp + (((size_t)r0.x) << ss) + fo);
            u16x8 v1 = *(const u16x8*)(gp + (((size_t)r1.x) << ss) + fo);
            float w0 = __int_as_float(r0.y), w1 = __int_as_float(r1.y);
            #pragma unroll
            for (int j = 0; j < 8; j++)
                a[j] += bf2f(v0[j]) * w0 + bf2f(v1[j]) * w1;
        }
        if (ee < hi) {
            int2 r0 = csr[ee];
            u16x8 v0 = *(const u16x8*)(gp + (((size_t)r0.x) << ss) + fo);
            float w0 = __int_as_float(r0.y);
            #pragma unroll
            for (int j = 0; j < 8; j++) a[j] += bf2f(v0[j]) * w0;
        }
    }
    #pragma unroll
    for (int st = 8; st < 64; st <<= 1)
        #pragma unroll
        for (int j = 0; j < 8; j++) a[j] += __shfl_xor(a[j], st);
    if (g == 0 && act) {
        float4 o0, o1;
        o0.x = a[0] + bias[f0 + 0]; o0.y = a[1] + bias[f0 + 1];
        o0.z = a[2] + bias[f0 + 2]; o0.w = a[3] + bias[f0 + 3];
        o1.x = a[4] + bias[f0 + 4]; o1.y = a[5] + bias[f0 + 5];
        o1.z = a[6] + bias[f0 + 6]; o1.w = a[7] + bias[f0 + 7];
        float* dst = out + (long)node * NC + f0;
        *(float4*)dst = o0;
        *(float4*)(dst + 4) = o1;
    }
}

// ---------------- launch ----------------

extern "C" void kernel_launch(void* const* d_in, const int* in_sizes, int n_in,
                              void* d_out, int out_size, void* d_ws, size_t ws_size,
                              hipStream_t stream) {
    const float* x     = (const float*)d_in[0];
    const int*   ei    = (const int*)d_in[1];
    const float* W_mlp = (const float*)d_in[2];
    const float* b_mlp = (const float*)d_in[3];
    const float* W1    = (const float*)d_in[4];
    const float* b1    = (const float*)d_in[5];
    const float* W2    = (const float*)d_in[6];
    const float* b2    = (const float*)d_in[7];
    float* out = (float*)d_out;

    // workspace layout (float units)
    float* ws = (float*)d_ws;
    size_t off = 0;
    float*    dis     = ws + off; off += 100096;
    int*      row_cnt = (int*)(ws + off); off += 100096;
    int*      row_ptr = (int*)(ws + off); off += 100096;
    int*      bsum    = (int*)(ws + off); off += 512;
    unsigned char* rpart8 = (unsigned char*)(ws + off); off += (size_t)PARTS * NPAD / 4;
    unsigned char* cpart8 = (unsigned char*)(ws + off); off += (size_t)PARTS * NPAD / 4;
    unsigned char* rbase8 = (unsigned char*)(ws + off); off += (size_t)PARTS * NPAD / 4;
    int2*     csr     = (int2*)(ws + off); off += (size_t)NE * 2;
    unsigned short* WTm = (unsigned short*)(ws + off); off += (NH * NF) / 2;
    unsigned short* W1T = (unsigned short*)(ws + off); off += (NH * NH) / 2;
    unsigned short* W2T = (unsigned short*)(ws + off); off += (64 * NH) / 2;
    unsigned short* t1  = (unsigned short*)(ws + off); off += (size_t)NN * NH / 2;
    unsigned short* h1  = (unsigned short*)(ws + off); off += (size_t)NN * NH / 2;
    unsigned short* t2A = (unsigned short*)(ws + off); off += (size_t)NN * 32 / 2;
    unsigned short* t2B = (unsigned short*)(ws + off); off += (size_t)NN * 8 / 2;
    (void)ws_size;

    // fused: histogram (256 blocks) + weight transpose (416 blocks)
    histw_kernel<<<2 * PARTS * 2 + WT_ELEMS / 512, 512, 0, stream>>>(
        ei, rpart8, cpart8, W_mlp, W1, W2, WTm, W1T, W2T);
    reduce_kernel<<<NBLK, 256, 0, stream>>>(rpart8, cpart8, row_cnt, dis, bsum);
    rstart2_kernel<<<NBLK, 256, 0, stream>>>(rpart8, row_cnt, bsum, row_ptr, rbase8);
    dim3 gf(NCH, PARTS);
    fill2d_kernel<<<gf, 512, 0, stream>>>(ei, rbase8, row_ptr, dis, csr);

    const int mb = (NN + 127) / 128;  // 782
    // t1 = (relu(x@Wm+b)) @ W1, fused (h0 stays in LDS)
    gemm12_kernel<<<mb, 512, 0, stream>>>(x, WTm, b_mlp, W1T, t1, NN);
    // h1 = relu(agg(t1) + b1)
    agg256_kernel<<<(NN + 3) / 4, 256, 0, stream>>>(t1, row_ptr, csr, dis, b1, h1, NN);
    // t2A/t2B = h1 @ W2 (split 32+8 planes)
    gemm3_kernel<<<mb, 256, 0, stream>>>(h1, W2T, t2A, t2B, NN);
    // out = agg(t2A,t2B) + b2
    agg40_kernel<<<(NN + 3) / 4, 256, 0, stream>>>(t2A, t2B, row_ptr, csr, dis, b2, out, NN);
}